// Round 1
// baseline (392.538 us; speedup 1.0000x reference)
//
#include <hip/hip_runtime.h>

#define N_NODES 100000
#define N_EDGES 1600000
#define D 128      // D_IN == D_HID
#define D_OUT 64
#define MAXDEG 64  // Poisson(16); max over 100k nodes ~35. 64 = safe pow2.

// prep grid: direct-CSR build ∪ f32->bf16/fp8 convert ∪ weight pack
#define NBLK_CSR 1563   // ceil((N_EDGES/4) int4-groups / 256)
#define NBLK_CVT 6250   // 1.6M uint4-groups / 256
#define NBLK_PACK 24    // 16 (Wp1) + 8 (Wp2)

typedef __attribute__((ext_vector_type(8))) short short8;   // 8 bf16 (4 VGPRs)
typedef __attribute__((ext_vector_type(4))) float floatx4;  // MFMA C/D
typedef __attribute__((ext_vector_type(2))) float floatx2;

__device__ inline unsigned short f2bf(float f) {   // RNE f32 -> bf16
    unsigned u = __builtin_bit_cast(unsigned, f);
    u = (u + 0x7fffu + ((u >> 16) & 1u)) >> 16;
    return (unsigned short)u;
}

// ---- pack W = [Wa;Wb] (K=256, ncols) into MFMA B-frag order (device helper) ----
__device__ inline void pack_dev(const float* __restrict__ Wa, const float* __restrict__ Wb,
                                int ncols, unsigned short* __restrict__ out, int t) {
    int nnt = ncols >> 4;
    int lane = t & 63;
    int nt = (t >> 6) % nnt;
    int kt = t / (64 * nnt);
    int col = nt * 16 + (lane & 15);
    int k0 = kt * 32 + ((lane >> 4) << 3);
    unsigned short* dstp = out + (size_t)((kt * nnt + nt) * 64 + lane) * 8;
    #pragma unroll
    for (int j = 0; j < 8; ++j) {
        int k = k0 + j;
        float f = (k < 128) ? Wa[(size_t)k * ncols + col]
                            : Wb[(size_t)(k - 128) * ncols + col];
        dstp[j] = f2bf(f);
    }
}

// ------- fused prep: direct padded-CSR build ∪ (f32->bf16+fp8) ∪ weight pack ------
// CSR build: padded rows (64 slots) mean NO prefix sum is needed — the global
// atomic's return value is the slot. 1.6M atomicAdds over 100K counters
// (avg 16/counter) is negligible contention; short uniform blocks replace the
// old 250-block multisplit latency tail, and the bucketbuf intermediate plus
// the entire bucket_csr dispatch disappear.
__global__ __launch_bounds__(256) void prep(
        const float* __restrict__ x, const int* __restrict__ src, const int* __restrict__ dst,
        const float* __restrict__ Ws1, const float* __restrict__ Wn1,
        const float* __restrict__ Ws2, const float* __restrict__ Wn2,
        unsigned short* __restrict__ xb, unsigned* __restrict__ xf8,
        int* __restrict__ dcount, int* __restrict__ csrp,
        unsigned short* __restrict__ Wp1, unsigned short* __restrict__ Wp2) {
    const int tid = threadIdx.x;
    const int b = blockIdx.x;

    if (b < NBLK_CSR) {
        // ---- direct CSR scatter: 4 edges/thread via int4 loads ----
        int g = b * 256 + tid;                 // int4-group id
        if (g < N_EDGES / 4) {
            int4 d4 = ((const int4*)dst)[g];
            int4 s4 = ((const int4*)src)[g];
            int dd[4] = {d4.x, d4.y, d4.z, d4.w};
            int ss[4] = {s4.x, s4.y, s4.z, s4.w};
            #pragma unroll
            for (int u = 0; u < 4; ++u) {
                int p = atomicAdd(&dcount[dd[u]], 1);
                if (p < MAXDEG)
                    csrp[((size_t)dd[u] << 6) + p] = ss[u];
            }
        }
    } else if (b < NBLK_CSR + NBLK_CVT) {
        // ---- f32 -> bf16 + fp8 (8 elems/thread) ----
        int i = (b - NBLK_CSR) * 256 + tid;    // < 1.6M exactly
        const float4* p = (const float4*)x + 2 * (size_t)i;
        float4 a = p[0], c = p[1];
        uint4 u;
        u.x = (unsigned)f2bf(a.x) | ((unsigned)f2bf(a.y) << 16);
        u.y = (unsigned)f2bf(a.z) | ((unsigned)f2bf(a.w) << 16);
        u.z = (unsigned)f2bf(c.x) | ((unsigned)f2bf(c.y) << 16);
        u.w = (unsigned)f2bf(c.z) | ((unsigned)f2bf(c.w) << 16);
        ((uint4*)xb)[i] = u;
        int v0 = __builtin_amdgcn_cvt_pk_fp8_f32(a.x, a.y, 0, false);
        v0     = __builtin_amdgcn_cvt_pk_fp8_f32(a.z, a.w, v0, true);
        int v1 = __builtin_amdgcn_cvt_pk_fp8_f32(c.x, c.y, 0, false);
        v1     = __builtin_amdgcn_cvt_pk_fp8_f32(c.z, c.w, v1, true);
        uint2 w8; w8.x = (unsigned)v0; w8.y = (unsigned)v1;
        ((uint2*)xf8)[i] = w8;
    } else {
        // ---- weight pack ----
        int sub = b - (NBLK_CSR + NBLK_CVT);
        if (sub < 16) pack_dev(Ws1, Wn1, D, Wp1, sub * 256 + tid);
        else          pack_dev(Ws2, Wn2, D_OUT, Wp2, (sub - 16) * 256 + tid);
    }
}

// ------- mean aggregation (fp8 gather): one wave per node, 2 edges per load -------
// The padded CSR row (64 ints) is loaded ONCE via row[lane]; indices are then
// broadcast register-to-register with __shfl (ds_bpermute). No memory-dependent
// index stage between gathers -> all dg gathers issue back-to-back.
__global__ __launch_bounds__(256) void agg_fp8(
        const unsigned char* __restrict__ feat, const int* __restrict__ csrp,
        const int* __restrict__ dcount, unsigned short* __restrict__ out) {
    int w = (blockIdx.x * 256 + threadIdx.x) >> 6;
    int lane = threadIdx.x & 63;
    if (w >= N_NODES) return;
    int dg = __builtin_amdgcn_readfirstlane(dcount[w]);
    if (dg > MAXDEG) dg = MAXDEG;      // dcount is unclamped now (never hits on this data)
    const int half = lane >> 5;
    const int c4 = (lane & 31) << 2;   // column base (x4 fp8)
    int idxv = csrp[((size_t)w << 6) + lane];   // whole padded row, one load
    float a0 = 0.f, a1 = 0.f, a2 = 0.f, a3 = 0.f;
    int j = 0;
    for (; j + 8 <= dg; j += 8) {      // 4 pairs = 8 edges in flight
        int s[4]; unsigned v[4];
        #pragma unroll
        for (int u = 0; u < 4; ++u) s[u] = __shfl(idxv, j + 2 * u + half);
        #pragma unroll
        for (int u = 0; u < 4; ++u)
            v[u] = *(const unsigned*)(feat + ((size_t)s[u] << 7) + c4);
        #pragma unroll
        for (int u = 0; u < 4; ++u) {
            floatx2 lo = __builtin_amdgcn_cvt_pk_f32_fp8(v[u], false);
            floatx2 hi = __builtin_amdgcn_cvt_pk_f32_fp8(v[u], true);
            a0 += lo.x; a1 += lo.y; a2 += hi.x; a3 += hi.y;
        }
    }
    for (; j + 2 <= dg; j += 2) {      // remaining pairs (register-fed)
        int s = __shfl(idxv, j + half);
        unsigned v = *(const unsigned*)(feat + ((size_t)s << 7) + c4);
        floatx2 lo = __builtin_amdgcn_cvt_pk_f32_fp8(v, false);
        floatx2 hi = __builtin_amdgcn_cvt_pk_f32_fp8(v, true);
        a0 += lo.x; a1 += lo.y; a2 += hi.x; a3 += hi.y;
    }
    if (j < dg) {                      // odd tail: uniform shuffle, half==0 loads
        int s = __shfl(idxv, j);
        if (half == 0) {
            unsigned v = *(const unsigned*)(feat + ((size_t)s << 7) + c4);
            floatx2 lo = __builtin_amdgcn_cvt_pk_f32_fp8(v, false);
            floatx2 hi = __builtin_amdgcn_cvt_pk_f32_fp8(v, true);
            a0 += lo.x; a1 += lo.y; a2 += hi.x; a3 += hi.y;
        }
    }
    // fold odd-parity partial sums into lanes 0-31
    a0 += __shfl_down(a0, 32); a1 += __shfl_down(a1, 32);
    a2 += __shfl_down(a2, 32); a3 += __shfl_down(a3, 32);
    if (half == 0) {
        float invd = (dg > 0) ? 1.0f / (float)dg : 1.0f;
        uint2 pv;
        pv.x = (unsigned)f2bf(a0 * invd) | ((unsigned)f2bf(a1 * invd) << 16);
        pv.y = (unsigned)f2bf(a2 * invd) | ((unsigned)f2bf(a3 * invd) << 16);
        *(uint2*)(out + (size_t)w * D + c4) = pv;   // 32 lanes x 8 B = full row
    }
}

// ---------------- fused SAGE dense layer: C = act([A0 | A1] @ Wp + bias) ------
// Optionally also emits an fp8 copy of C (for the next layer's gather).
template<int NT, bool RELU, bool OUT_BF16, bool WFP8>
__global__ __launch_bounds__(256) void gemm_sage(
        const unsigned short* __restrict__ A0, const unsigned short* __restrict__ A1,
        const unsigned short* __restrict__ Wp, const float* __restrict__ bias,
        void* __restrict__ Cout, unsigned char* __restrict__ C8)
{
    const int wave = threadIdx.x >> 6;
    const int lane = threadIdx.x & 63;
    const int q = lane >> 4, m = lane & 15;
    const int NCOL = NT * 16;

    int row = blockIdx.x * 64 + wave * 16 + m;
    int rowc = (row < N_NODES) ? row : (N_NODES - 1);

    floatx4 acc[NT];
    #pragma unroll
    for (int nt = 0; nt < NT; ++nt) acc[nt] = (floatx4){0.f, 0.f, 0.f, 0.f};

    #pragma unroll
    for (int kt = 0; kt < 8; ++kt) {
        const unsigned short* __restrict__ base = (kt < 4) ? A0 : A1;
        short8 af = *(const short8*)(base + (size_t)rowc * D + (kt & 3) * 32 + q * 8);
        #pragma unroll
        for (int nt = 0; nt < NT; ++nt) {
            short8 bf = *(const short8*)(Wp + (size_t)((kt * NT + nt) * 64 + lane) * 8);
            acc[nt] = __builtin_amdgcn_mfma_f32_16x16x32_bf16(af, bf, acc[nt], 0, 0, 0);
        }
    }

    const int orow_base = blockIdx.x * 64 + wave * 16 + q * 4;
    #pragma unroll
    for (int nt = 0; nt < NT; ++nt) {
        float b = bias[nt * 16 + m];
        #pragma unroll
        for (int i = 0; i < 4; ++i) {
            int orow = orow_base + i;
            if (orow < N_NODES) {
                float v = acc[nt][i] + b;
                if (RELU) v = fmaxf(v, 0.f);
                if (OUT_BF16)
                    ((unsigned short*)Cout)[(size_t)orow * NCOL + nt * 16 + m] = f2bf(v);
                else
                    ((float*)Cout)[(size_t)orow * NCOL + nt * 16 + m] = v;
                if (WFP8) {
                    int pk = __builtin_amdgcn_cvt_pk_fp8_f32(v, v, 0, false);
                    C8[(size_t)orow * NCOL + nt * 16 + m] = (unsigned char)(pk & 0xff);
                }
            }
        }
    }
}

extern "C" void kernel_launch(void* const* d_in, const int* in_sizes, int n_in,
                              void* d_out, int out_size, void* d_ws, size_t ws_size,
                              hipStream_t stream) {
    const float* x   = (const float*)d_in[0];
    const int*   src = (const int*)d_in[1];
    const int*   dst = (const int*)d_in[2];
    const float* Ws1 = (const float*)d_in[3];
    const float* Wn1 = (const float*)d_in[4];
    const float* b1  = (const float*)d_in[5];
    const float* Ws2 = (const float*)d_in[6];
    const float* Wn2 = (const float*)d_in[7];
    const float* b2  = (const float*)d_in[8];
    float* out = (float*)d_out;

    const size_t nd = (size_t)N_NODES * D;   // 12.8M elements
    unsigned short* xb   = (unsigned short*)d_ws;      // bf16 x          (25.6 MB)
    unsigned short* h    = xb + nd;                    // bf16 hidden     (25.6 MB)
    unsigned short* aggb = h + nd;                     // bf16 aggregate  (25.6 MB)
    unsigned char*  xf8  = (unsigned char*)(aggb + nd);// fp8 x           (12.8 MB)
    unsigned char*  hf8  = xf8 + nd;                   // fp8 hidden      (12.8 MB)
    int* dcount = (int*)(hf8 + nd);                    //                 (0.4 MB)
    int* csrp   = dcount + N_NODES;                    // padded CSR      (25.6 MB)
    unsigned short* Wp1 = (unsigned short*)(csrp + (size_t)N_NODES * MAXDEG);
    unsigned short* Wp2 = Wp1 + 32768;

    hipMemsetAsync(dcount, 0, N_NODES * sizeof(int), stream);

    prep<<<NBLK_CSR + NBLK_CVT + NBLK_PACK, 256, 0, stream>>>(
        x, src, dst, Ws1, Wn1, Ws2, Wn2, xb, (unsigned*)xf8, dcount, csrp, Wp1, Wp2);

    const int agg_blocks = (N_NODES * 64 + 255) / 256;   // 25000
    const int gemm_blocks = (N_NODES + 63) / 64;         // 1563

    agg_fp8<<<agg_blocks, 256, 0, stream>>>(xf8, csrp, dcount, aggb);
    gemm_sage<8, true, true, true><<<gemm_blocks, 256, 0, stream>>>(xb, aggb, Wp1, b1, h, hf8);
    agg_fp8<<<agg_blocks, 256, 0, stream>>>(hf8, csrp, dcount, aggb);
    gemm_sage<4, false, false, false><<<gemm_blocks, 256, 0, stream>>>(h, aggb, Wp2, b2, out, nullptr);
}

// Round 2
// 347.130 us; speedup vs baseline: 1.1308x; 1.1308x over previous
//
#include <hip/hip_runtime.h>

#define N_NODES 100000
#define N_EDGES 1600000
#define D 128      // D_IN == D_HID
#define D_OUT 64
#define MAXDEG 64  // Poisson(16); max over 100k nodes ~35. 64 = safe pow2.

// Bucketed CSR build (multisplit): REQUIRED for write locality — round-1's
// direct global-atomic scatter caused 16x write amplification (WRITE_SIZE
// 45->134 MB) from random 4B writes across a 25.6MB region.
#define NBUCK 782          // buckets of 128 nodes: ceil(100000/128)
#define BSHIFT 7           // 128 nodes per bucket
#define BCAP  3072         // avg 2046 edges/bucket, +10 sigma slack
#define CHUNK 6400         // edges per split block; 250*6400 = 1.6M exact
#define NBLK_A (N_EDGES / CHUNK)            // 250
#define NBLK_CVT 6250                        // 1.6M fp8x8-groups / 256
#define NBLK_PACK 24                         // 16 (Wp1) + 8 (Wp2)

#define LDSPAD 136  // shorts per LDS agg row; 272B stride -> (17r+q)%8 uniform,
                    // conflict-free ds_read_b128 for the MFMA A1 fragments

typedef __attribute__((ext_vector_type(8))) short short8;   // 8 bf16 (4 VGPRs)
typedef __attribute__((ext_vector_type(4))) float floatx4;  // MFMA C/D
typedef __attribute__((ext_vector_type(2))) float floatx2;

__device__ inline unsigned short f2bf(float f) {   // RNE f32 -> bf16
    unsigned u = __builtin_bit_cast(unsigned, f);
    u = (u + 0x7fffu + ((u >> 16) & 1u)) >> 16;
    return (unsigned short)u;
}

// ---- pack W = [Wa;Wb] (K=256, ncols) into MFMA B-frag order (device helper) ----
__device__ inline void pack_dev(const float* __restrict__ Wa, const float* __restrict__ Wb,
                                int ncols, unsigned short* __restrict__ out, int t) {
    int nnt = ncols >> 4;
    int lane = t & 63;
    int nt = (t >> 6) % nnt;
    int kt = t / (64 * nnt);
    int col = nt * 16 + (lane & 15);
    int k0 = kt * 32 + ((lane >> 4) << 3);
    unsigned short* dstp = out + (size_t)((kt * nnt + nt) * 64 + lane) * 8;
    #pragma unroll
    for (int j = 0; j < 8; ++j) {
        int k = k0 + j;
        float f = (k < 128) ? Wa[(size_t)k * ncols + col]
                            : Wb[(size_t)(k - 128) * ncols + col];
        dstp[j] = f2bf(f);
    }
}

// ------- fused prep: bucket multisplit ∪ (f32->fp8 convert) ∪ weight pack -------
__global__ __launch_bounds__(256) void prep(
        const float* __restrict__ x, const int* __restrict__ src, const int* __restrict__ dst,
        const float* __restrict__ Ws1, const float* __restrict__ Wn1,
        const float* __restrict__ Ws2, const float* __restrict__ Wn2,
        unsigned* __restrict__ xf8,
        int* __restrict__ gcur, int* __restrict__ bucketbuf,
        unsigned short* __restrict__ Wp1, unsigned short* __restrict__ Wp2) {
    __shared__ int cnt[NBUCK];
    __shared__ int base_s[NBUCK];
    const int tid = threadIdx.x;
    const int b = blockIdx.x;

    if (b < NBLK_A) {
        // ---- phase A multisplit: dense run-writes, write amplification ~1 ----
        for (int i = tid; i < NBUCK; i += 256) cnt[i] = 0;
        __syncthreads();
        const int e0 = b * CHUNK;
        for (int i = tid; i < CHUNK; i += 256) {
            int d = __builtin_nontemporal_load(dst + e0 + i);
            atomicAdd(&cnt[d >> BSHIFT], 1);
        }
        __syncthreads();
        for (int i = tid; i < NBUCK; i += 256) {
            int c = cnt[i];
            base_s[i] = c ? atomicAdd(&gcur[i], c) : 0;
            cnt[i] = 0;   // reuse as per-block write cursor
        }
        __syncthreads();
        for (int i = tid; i < CHUNK; i += 256) {
            int d = __builtin_nontemporal_load(dst + e0 + i);
            int s = __builtin_nontemporal_load(src + e0 + i);
            int bk = d >> BSHIFT;
            int p = base_s[bk] + atomicAdd(&cnt[bk], 1);
            if (p < BCAP)   // statically impossible overflow; safety net
                bucketbuf[bk * BCAP + p] = ((d & 127) << 17) | s;
        }
    } else if (b < NBLK_A + NBLK_CVT) {
        // ---- f32 -> fp8 (8 elems/thread); bf16 x is no longer materialized ----
        int i = (b - NBLK_A) * 256 + tid;   // < 1.6M exactly
        const float4* p = (const float4*)x + 2 * (size_t)i;
        float4 a = p[0], c = p[1];
        int v0 = __builtin_amdgcn_cvt_pk_fp8_f32(a.x, a.y, 0, false);
        v0     = __builtin_amdgcn_cvt_pk_fp8_f32(a.z, a.w, v0, true);
        int v1 = __builtin_amdgcn_cvt_pk_fp8_f32(c.x, c.y, 0, false);
        v1     = __builtin_amdgcn_cvt_pk_fp8_f32(c.z, c.w, v1, true);
        uint2 w8; w8.x = (unsigned)v0; w8.y = (unsigned)v1;
        ((uint2*)xf8)[i] = w8;
    } else {
        // ---- weight pack ----
        int sub = b - (NBLK_A + NBLK_CVT);
        if (sub < 16) pack_dev(Ws1, Wn1, D, Wp1, sub * 256 + tid);
        else          pack_dev(Ws2, Wn2, D_OUT, Wp2, (sub - 16) * 256 + tid);
    }
}

// ------- phase B: per-bucket CSR build via LDS counters (no global atomics) -------
// 782 blocks (was 196): ~3x more blocks kills the latency tail; per-bucket CSR
// region is 32KB -> scatter writes stay L2-hot.
__global__ __launch_bounds__(256) void bucket_csr(
        const int* __restrict__ gcur, const int* __restrict__ bucketbuf,
        int* __restrict__ dcount, int* __restrict__ csrp) {
    __shared__ int lcnt[128];
    const int tid = threadIdx.x, b = blockIdx.x;
    if (tid < 128) lcnt[tid] = 0;
    __syncthreads();
    int m = gcur[b]; if (m > BCAP) m = BCAP;
    const int* __restrict__ buf = bucketbuf + b * BCAP;
    for (int i = tid; i < m; i += 256) {
        int v = buf[i];
        int dloc = v >> 17, s = v & 0x1FFFF;
        int slot = atomicAdd(&lcnt[dloc], 1);
        if (slot < MAXDEG)
            csrp[(((size_t)(b << BSHIFT) + dloc) << 6) + slot] = s;
    }
    __syncthreads();
    if (tid < 128) {
        int node = (b << BSHIFT) + tid;
        if (node < N_NODES) {
            int c = lcnt[tid];
            dcount[node] = (c > MAXDEG) ? MAXDEG : c;
        }
    }
}

// ------------- fused SAGE layer: mean-agg (fp8 gather -> LDS) + MFMA GEMM -------
// Phase 1: each wave aggregates 16 nodes (one at a time, 64 lanes on one node,
//   2 edges per load, 8 edges in flight) into a padded LDS tile (bf16).
// Phase 2: C = act([A0 | LDS_agg] @ Wp + bias). A0 is read directly from
//   global (f32 x with on-the-fly bf16 convert for layer 1, bf16 h for layer 2).
// This removes the aggb materialization (2 x 51.2MB round trip) and xb.
template<int NT, bool RELU, bool A0F32, bool OUT_BF16, bool WFP8>
__global__ __launch_bounds__(256) void fused_sage(
        const void* __restrict__ A0,
        const unsigned char* __restrict__ feat, const int* __restrict__ csrp,
        const int* __restrict__ dcount,
        const unsigned short* __restrict__ Wp, const float* __restrict__ bias,
        void* __restrict__ Cout, unsigned char* __restrict__ C8)
{
    __shared__ unsigned short lds_agg[64 * LDSPAD];
    const int wave = threadIdx.x >> 6;
    const int lane = threadIdx.x & 63;
    const int half = lane >> 5;
    const int c4 = (lane & 31) << 2;   // column base (x4 fp8)

    // ---- phase 1: aggregate; wave handles nodes b*64 + wave*16 + (0..15) ----
    for (int t = 0; t < 16; ++t) {
        const int n = blockIdx.x * 64 + wave * 16 + t;
        float a0 = 0.f, a1 = 0.f, a2 = 0.f, a3 = 0.f;
        int dg = 0;
        if (n < N_NODES) {
            dg = __builtin_amdgcn_readfirstlane(dcount[n]);
            int idxv = csrp[((size_t)n << 6) + lane];   // whole padded row
            int j = 0;
            for (; j + 8 <= dg; j += 8) {      // 4 pairs = 8 edges in flight
                int s[4]; unsigned v[4];
                #pragma unroll
                for (int u = 0; u < 4; ++u) s[u] = __shfl(idxv, j + 2 * u + half);
                #pragma unroll
                for (int u = 0; u < 4; ++u)
                    v[u] = *(const unsigned*)(feat + ((size_t)s[u] << 7) + c4);
                #pragma unroll
                for (int u = 0; u < 4; ++u) {
                    floatx2 lo = __builtin_amdgcn_cvt_pk_f32_fp8(v[u], false);
                    floatx2 hi = __builtin_amdgcn_cvt_pk_f32_fp8(v[u], true);
                    a0 += lo.x; a1 += lo.y; a2 += hi.x; a3 += hi.y;
                }
            }
            for (; j + 2 <= dg; j += 2) {      // remaining pairs
                int s = __shfl(idxv, j + half);
                unsigned v = *(const unsigned*)(feat + ((size_t)s << 7) + c4);
                floatx2 lo = __builtin_amdgcn_cvt_pk_f32_fp8(v, false);
                floatx2 hi = __builtin_amdgcn_cvt_pk_f32_fp8(v, true);
                a0 += lo.x; a1 += lo.y; a2 += hi.x; a3 += hi.y;
            }
            if (j < dg) {                      // odd tail
                int s = __shfl(idxv, j);
                if (half == 0) {
                    unsigned v = *(const unsigned*)(feat + ((size_t)s << 7) + c4);
                    floatx2 lo = __builtin_amdgcn_cvt_pk_f32_fp8(v, false);
                    floatx2 hi = __builtin_amdgcn_cvt_pk_f32_fp8(v, true);
                    a0 += lo.x; a1 += lo.y; a2 += hi.x; a3 += hi.y;
                }
            }
        }
        // fold odd-parity partials into lanes 0-31, write LDS row (bf16)
        a0 += __shfl_down(a0, 32); a1 += __shfl_down(a1, 32);
        a2 += __shfl_down(a2, 32); a3 += __shfl_down(a3, 32);
        if (half == 0) {
            float invd = (dg > 0) ? 1.0f / (float)dg : 1.0f;
            uint2 pv;
            pv.x = (unsigned)f2bf(a0 * invd) | ((unsigned)f2bf(a1 * invd) << 16);
            pv.y = (unsigned)f2bf(a2 * invd) | ((unsigned)f2bf(a3 * invd) << 16);
            *(uint2*)(&lds_agg[(wave * 16 + t) * LDSPAD + c4]) = pv;
        }
    }
    __syncthreads();

    // ---- phase 2: MFMA GEMM over K=256 = [A0(128) | agg(128)] ----
    const int q = lane >> 4, m = lane & 15;
    const int NCOL = NT * 16;
    const int row = blockIdx.x * 64 + wave * 16 + m;
    const int rowc = (row < N_NODES) ? row : (N_NODES - 1);

    floatx4 acc[NT];
    #pragma unroll
    for (int nt = 0; nt < NT; ++nt) acc[nt] = (floatx4){0.f, 0.f, 0.f, 0.f};

    #pragma unroll
    for (int kt = 0; kt < 8; ++kt) {
        short8 af;
        if (kt < 4) {
            if (A0F32) {
                const float* xr = (const float*)A0 + (size_t)rowc * D + kt * 32 + q * 8;
                float4 f0 = *(const float4*)xr;
                float4 f1 = *(const float4*)(xr + 4);
                af[0] = (short)f2bf(f0.x); af[1] = (short)f2bf(f0.y);
                af[2] = (short)f2bf(f0.z); af[3] = (short)f2bf(f0.w);
                af[4] = (short)f2bf(f1.x); af[5] = (short)f2bf(f1.y);
                af[6] = (short)f2bf(f1.z); af[7] = (short)f2bf(f1.w);
            } else {
                af = *(const short8*)((const unsigned short*)A0 +
                                      (size_t)rowc * D + kt * 32 + q * 8);
            }
        } else {
            af = *(const short8*)(&lds_agg[(wave * 16 + m) * LDSPAD +
                                           (kt & 3) * 32 + q * 8]);
        }
        #pragma unroll
        for (int nt = 0; nt < NT; ++nt) {
            short8 bf = *(const short8*)(Wp + (size_t)((kt * NT + nt) * 64 + lane) * 8);
            acc[nt] = __builtin_amdgcn_mfma_f32_16x16x32_bf16(af, bf, acc[nt], 0, 0, 0);
        }
    }

    const int orow_base = blockIdx.x * 64 + wave * 16 + q * 4;
    #pragma unroll
    for (int nt = 0; nt < NT; ++nt) {
        float bv = bias[nt * 16 + m];
        #pragma unroll
        for (int i = 0; i < 4; ++i) {
            int orow = orow_base + i;
            if (orow < N_NODES) {
                float v = acc[nt][i] + bv;
                if (RELU) v = fmaxf(v, 0.f);
                if (OUT_BF16)
                    ((unsigned short*)Cout)[(size_t)orow * NCOL + nt * 16 + m] = f2bf(v);
                else
                    ((float*)Cout)[(size_t)orow * NCOL + nt * 16 + m] = v;
                if (WFP8) {
                    int pk = __builtin_amdgcn_cvt_pk_fp8_f32(v, v, 0, false);
                    C8[(size_t)orow * NCOL + nt * 16 + m] = (unsigned char)(pk & 0xff);
                }
            }
        }
    }
}

extern "C" void kernel_launch(void* const* d_in, const int* in_sizes, int n_in,
                              void* d_out, int out_size, void* d_ws, size_t ws_size,
                              hipStream_t stream) {
    const float* x   = (const float*)d_in[0];
    const int*   src = (const int*)d_in[1];
    const int*   dst = (const int*)d_in[2];
    const float* Ws1 = (const float*)d_in[3];
    const float* Wn1 = (const float*)d_in[4];
    const float* b1  = (const float*)d_in[5];
    const float* Ws2 = (const float*)d_in[6];
    const float* Wn2 = (const float*)d_in[7];
    const float* b2  = (const float*)d_in[8];
    float* out = (float*)d_out;

    const size_t nd = (size_t)N_NODES * D;   // 12.8M elements
    unsigned short* h   = (unsigned short*)d_ws;       // bf16 hidden     (25.6 MB)
    unsigned char*  xf8 = (unsigned char*)(h + nd);    // fp8 x           (12.8 MB)
    unsigned char*  hf8 = xf8 + nd;                    // fp8 hidden      (12.8 MB)
    int* dcount = (int*)(hf8 + nd);                    //                 (0.4 MB)
    int* csrp   = dcount + N_NODES;                    // padded CSR      (25.6 MB)
    int* gcur   = csrp + (size_t)N_NODES * MAXDEG;     // bucket cursors  (pad 4KB)
    int* bucketbuf = gcur + 1024;                      // bucket edges    (9.6 MB)
    unsigned short* Wp1 = (unsigned short*)(bucketbuf + (size_t)NBUCK * BCAP);
    unsigned short* Wp2 = Wp1 + 32768;

    hipMemsetAsync(gcur, 0, NBUCK * sizeof(int), stream);

    prep<<<NBLK_A + NBLK_CVT + NBLK_PACK, 256, 0, stream>>>(
        x, src, dst, Ws1, Wn1, Ws2, Wn2, (unsigned*)xf8, gcur, bucketbuf, Wp1, Wp2);
    bucket_csr<<<NBUCK, 256, 0, stream>>>(gcur, bucketbuf, dcount, csrp);

    const int fused_blocks = (N_NODES + 63) / 64;        // 1563
    fused_sage<8, true,  true,  true,  true ><<<fused_blocks, 256, 0, stream>>>(
        x, xf8, csrp, dcount, Wp1, b1, h, hf8);
    fused_sage<4, false, false, false, false><<<fused_blocks, 256, 0, stream>>>(
        h, hf8, csrp, dcount, Wp2, b2, out, nullptr);
}

// Round 4
// 319.980 us; speedup vs baseline: 1.2268x; 1.0848x over previous
//
#include <hip/hip_runtime.h>

#define N_NODES 100000
#define N_EDGES 1600000
#define D 128      // D_IN == D_HID
#define D_OUT 64
#define MAXDEG 64  // Poisson(16); max over 100k nodes ~35. 64 = safe pow2.

// Bucketed CSR build (multisplit) — REQUIRED for scatter write locality
// (round-1 direct atomics: 16x write amplification, WRITE 45->134MB).
#define NBUCK 782          // buckets of 128 nodes
#define BSHIFT 7
#define BCAP  3072         // avg 2046 edges/bucket, ~10 sigma slack
#define NBLK_SPLIT 500
#define CHUNK 3200         // 500*3200 = 1.6M exact
#define NBLK_CSR NBUCK     // 782
#define NBLK_CVT 6250      // 12.8M elems / 8 per thread / 256
#define NBLK_PACK 24       // 16 (Wp1: K=128,N=256) + 8 (Wp2: K=128,N=128)

typedef __attribute__((ext_vector_type(8))) short short8;   // 8 bf16 (4 VGPRs)
typedef __attribute__((ext_vector_type(4))) float floatx4;  // MFMA C/D
typedef __attribute__((ext_vector_type(2))) float floatx2;

__device__ inline unsigned short f2bf(float f) {   // RNE f32 -> bf16
    unsigned u = __builtin_bit_cast(unsigned, f);
    u = (u + 0x7fffu + ((u >> 16) & 1u)) >> 16;
    return (unsigned short)u;
}
__device__ inline float bf2f(unsigned short u) {
    return __builtin_bit_cast(float, (unsigned)u << 16);
}

// ---- pack W = [Wa | Wb] (N-concat, K=128) into MFMA B-frag order ----
__device__ inline void pack_ncat(const float* __restrict__ Wa, const float* __restrict__ Wb,
                                 int ncA, int ncB, unsigned short* __restrict__ out, int t) {
    int nnt = (ncA + ncB) >> 4;
    int lane = t & 63;
    int nt = (t >> 6) % nnt;
    int kt = t / (64 * nnt);                 // 0..3 (K=128)
    int col = nt * 16 + (lane & 15);
    int k0 = kt * 32 + ((lane >> 4) << 3);
    const float* W = (col < ncA) ? Wa : Wb;
    int nc = (col < ncA) ? ncA : ncB;
    int c  = (col < ncA) ? col : col - ncA;
    unsigned short* dstp = out + (size_t)((kt * nnt + nt) * 64 + lane) * 8;
    #pragma unroll
    for (int j = 0; j < 8; ++j)
        dstp[j] = f2bf(W[(size_t)(k0 + j) * nc + c]);
}

// ---------------- phase A: multisplit edges into 128-node buckets ----------------
__global__ __launch_bounds__(256) void split_k(
        const int* __restrict__ src, const int* __restrict__ dst,
        int* __restrict__ gcur, int* __restrict__ bucketbuf) {
    __shared__ int cnt[NBUCK];
    __shared__ int base_s[NBUCK];
    __shared__ int dstc[CHUNK];    // cache dst chunk: read HBM once, not twice
    const int tid = threadIdx.x;
    const int e0 = blockIdx.x * CHUNK;
    for (int i = tid; i < NBUCK; i += 256) cnt[i] = 0;
    __syncthreads();
    for (int i = tid; i < CHUNK; i += 256) {
        int d = __builtin_nontemporal_load(dst + e0 + i);
        dstc[i] = d;
        atomicAdd(&cnt[d >> BSHIFT], 1);
    }
    __syncthreads();
    for (int i = tid; i < NBUCK; i += 256) {
        int c = cnt[i];
        base_s[i] = c ? atomicAdd(&gcur[i], c) : 0;
        cnt[i] = 0;   // reuse as per-block write cursor
    }
    __syncthreads();
    for (int i = tid; i < CHUNK; i += 256) {
        int d = dstc[i];
        int s = __builtin_nontemporal_load(src + e0 + i);
        int bk = d >> BSHIFT;
        int p = base_s[bk] + atomicAdd(&cnt[bk], 1);
        if (p < BCAP)   // statically impossible overflow; safety net
            bucketbuf[bk * BCAP + p] = ((d & 127) << 17) | s;
    }
}

// -------- phase B fused: bucket CSR build ∪ f32->bf16 convert ∪ weight pack ------
__global__ __launch_bounds__(256) void prep2(
        const float* __restrict__ x,
        const int* __restrict__ gcur, const int* __restrict__ bucketbuf,
        const float* __restrict__ Ws1, const float* __restrict__ Wn1,
        const float* __restrict__ Ws2, const float* __restrict__ Wn2,
        unsigned short* __restrict__ xb,
        int* __restrict__ dcount, int* __restrict__ csrp,
        unsigned short* __restrict__ Wp1, unsigned short* __restrict__ Wp2) {
    const int tid = threadIdx.x, b = blockIdx.x;
    if (b < NBLK_CSR) {
        __shared__ int lcnt[128];
        if (tid < 128) lcnt[tid] = 0;
        __syncthreads();
        int m = gcur[b]; if (m > BCAP) m = BCAP;
        const int* __restrict__ buf = bucketbuf + b * BCAP;
        for (int i = tid; i < m; i += 256) {
            int v = buf[i];
            int dloc = (v >> 17) & 127, s = v & 0x1FFFF;
            int node = (b << BSHIFT) + dloc;
            int slot = atomicAdd(&lcnt[dloc], 1);
            if (slot < MAXDEG && node < N_NODES)
                csrp[((size_t)node << 6) + slot] = s;
        }
        __syncthreads();
        if (tid < 128) {
            int node = (b << BSHIFT) + tid;
            if (node < N_NODES) {
                int c = lcnt[tid]; if (c > MAXDEG) c = MAXDEG;
                dcount[node] = c;
                // zero-fill to next multiple of 16: agg's masked loads then
                // always read a VALID node index (0) in padding slots.
                int cf = (c + 15) & ~15; if (cf > MAXDEG) cf = MAXDEG;
                int* row = csrp + ((size_t)node << 6);
                for (int k = c; k < cf; ++k) row[k] = 0;
            }
        }
    } else if (b < NBLK_CSR + NBLK_CVT) {
        // ---- f32 -> bf16 (8 elems/thread) ----
        int i = (b - NBLK_CSR) * 256 + tid;   // < 1.6M exactly
        const float4* p = (const float4*)x + 2 * (size_t)i;
        float4 a = p[0], c = p[1];
        uint4 u;
        u.x = (unsigned)f2bf(a.x) | ((unsigned)f2bf(a.y) << 16);
        u.y = (unsigned)f2bf(a.z) | ((unsigned)f2bf(a.w) << 16);
        u.z = (unsigned)f2bf(c.x) | ((unsigned)f2bf(c.y) << 16);
        u.w = (unsigned)f2bf(c.z) | ((unsigned)f2bf(c.w) << 16);
        ((uint4*)xb)[i] = u;
    } else {
        int sub = b - (NBLK_CSR + NBLK_CVT);
        if (sub < 16) pack_ncat(Ws1, Wn1, D, D, Wp1, sub * 256 + tid);
        else          pack_ncat(Ws2, Wn2, D_OUT, D_OUT, Wp2, (sub - 16) * 256 + tid);
    }
}

// ------------- dual-output GEMM: [self+bias | nbr] = A @ [Ws | Wn], K=128 -------
// self (cols < NTA*16) gets +bias, written bf16 (L1) or f32 (L2).
// nbr  (cols >= NTA*16) written fp8 — the next gather's table. Mean-agg commutes
// with the linear map, so aggregating z = h@Wn AFTER the GEMM shrinks the
// layer-2 gather rows to 64B from a 6.4MB (L2-resident) table.
template<int NTA, int NTB, bool OUTA_BF16>
__global__ __launch_bounds__(256) void gemm_dual(
        const unsigned short* __restrict__ A, const unsigned short* __restrict__ Wp,
        const float* __restrict__ bias, void* __restrict__ OutA,
        unsigned char* __restrict__ OutB)
{
    const int NT = NTA + NTB;
    const int wave = threadIdx.x >> 6;
    const int lane = threadIdx.x & 63;
    const int q = lane >> 4, m = lane & 15;

    int row = blockIdx.x * 64 + wave * 16 + m;
    int rowc = (row < N_NODES) ? row : (N_NODES - 1);

    floatx4 acc[NT];
    #pragma unroll
    for (int nt = 0; nt < NT; ++nt) acc[nt] = (floatx4){0.f, 0.f, 0.f, 0.f};

    #pragma unroll
    for (int kt = 0; kt < 4; ++kt) {
        short8 af = *(const short8*)(A + (size_t)rowc * D + kt * 32 + q * 8);
        #pragma unroll
        for (int nt = 0; nt < NT; ++nt) {
            short8 bf = *(const short8*)(Wp + (size_t)((kt * NT + nt) * 64 + lane) * 8);
            acc[nt] = __builtin_amdgcn_mfma_f32_16x16x32_bf16(af, bf, acc[nt], 0, 0, 0);
        }
    }

    const int orow_base = blockIdx.x * 64 + wave * 16 + q * 4;
    #pragma unroll
    for (int nt = 0; nt < NT; ++nt) {
        float bv = (nt < NTA) ? bias[nt * 16 + m] : 0.f;
        #pragma unroll
        for (int i = 0; i < 4; ++i) {
            int orow = orow_base + i;
            if (orow < N_NODES) {
                float v = acc[nt][i];
                if (nt < NTA) {
                    v += bv;
                    if (OUTA_BF16)
                        ((unsigned short*)OutA)[(size_t)orow * (NTA * 16) + nt * 16 + m] = f2bf(v);
                    else
                        ((float*)OutA)[(size_t)orow * (NTA * 16) + nt * 16 + m] = v;
                } else {
                    int pk = __builtin_amdgcn_cvt_pk_fp8_f32(v, v, 0, false);
                    OutB[(size_t)orow * (NTB * 16) + (nt - NTA) * 16 + m] =
                        (unsigned char)(pk & 0xff);
                }
            }
        }
    }
}

// ---------- mean-agg + self-add: one wave per node, 8B/lane, 16 edges/iter ------
// L1: feat=y8 (128B rows), self=xs bf16, out=h bf16, ReLU.
// L2: feat=z8 (64B rows, L2-resident), self=tmp f32, out f32.
// csrp rows are zero-filled to mult-of-16, so all loads are safe; contributions
// of padding edges (e >= dg) are masked to fp8 0x00 == 0.0f before accumulate.
template<bool L1>
__global__ __launch_bounds__(256) void agg_add(
        const unsigned char* __restrict__ feat, const int* __restrict__ csrp,
        const int* __restrict__ dcount, const void* __restrict__ self,
        void* __restrict__ out)
{
    const int EPG = L1 ? 4 : 8;        // edges per load-group (64 lanes / LPE)
    const int LPE = 64 / EPG;          // lanes per edge (16 or 8)
    const int FSH = L1 ? 7 : 6;        // log2(row bytes)
    const int NC  = L1 ? 128 : 64;     // columns

    int w = (blockIdx.x * 256 + threadIdx.x) >> 6;
    int lane = threadIdx.x & 63;
    if (w >= N_NODES) return;
    int dg = __builtin_amdgcn_readfirstlane(dcount[w]);
    const int g = lane / LPE;          // edge slot within group
    const int l = lane % LPE;          // column octet
    int idxv = csrp[((size_t)w << 6) + lane];   // whole padded row, one load

    float a0 = 0.f, a1 = 0.f, a2 = 0.f, a3 = 0.f;
    float a4 = 0.f, a5 = 0.f, a6 = 0.f, a7 = 0.f;
    for (int j = 0; j < dg; j += 16) {
        #pragma unroll
        for (int u = 0; u < 16 / EPG; ++u) {
            int e = j + u * EPG + g;
            int s = __shfl(idxv, e);
            uint2 v = *(const uint2*)(feat + ((size_t)s << FSH) + (l << 3));
            bool ok = e < dg;
            unsigned vx = ok ? v.x : 0u;
            unsigned vy = ok ? v.y : 0u;
            floatx2 f0 = __builtin_amdgcn_cvt_pk_f32_fp8(vx, false);
            floatx2 f1 = __builtin_amdgcn_cvt_pk_f32_fp8(vx, true);
            floatx2 f2 = __builtin_amdgcn_cvt_pk_f32_fp8(vy, false);
            floatx2 f3 = __builtin_amdgcn_cvt_pk_f32_fp8(vy, true);
            a0 += f0.x; a1 += f0.y; a2 += f1.x; a3 += f1.y;
            a4 += f2.x; a5 += f2.y; a6 += f3.x; a7 += f3.y;
        }
    }
    // fold edge-slot groups: lanes with same l
    #pragma unroll
    for (int step = 0; step < 3; ++step) {
        int delta = 32 >> step;
        if (delta >= LPE) {
            a0 += __shfl_down(a0, delta); a1 += __shfl_down(a1, delta);
            a2 += __shfl_down(a2, delta); a3 += __shfl_down(a3, delta);
            a4 += __shfl_down(a4, delta); a5 += __shfl_down(a5, delta);
            a6 += __shfl_down(a6, delta); a7 += __shfl_down(a7, delta);
        }
    }
    if (g == 0) {                      // lanes 0..LPE-1 hold full sums
        float invd = (dg > 0) ? 1.0f / (float)dg : 1.0f;
        if (L1) {
            const unsigned short* sp = (const unsigned short*)self + (size_t)w * NC + l * 8;
            short8 sv = *(const short8*)sp;
            short8 hv;
            float acc[8] = {a0,a1,a2,a3,a4,a5,a6,a7};
            #pragma unroll
            for (int c = 0; c < 8; ++c) {
                float hval = bf2f((unsigned short)sv[c]) + acc[c] * invd;
                hval = fmaxf(hval, 0.f);
                hv[c] = (short)f2bf(hval);
            }
            *(short8*)((unsigned short*)out + (size_t)w * NC + l * 8) = hv;
        } else {
            const float* sp = (const float*)self + (size_t)w * NC + l * 8;
            float4 s0 = *(const float4*)sp;
            float4 s1 = *(const float4*)(sp + 4);
            float4 o0, o1;
            o0.x = s0.x + a0 * invd; o0.y = s0.y + a1 * invd;
            o0.z = s0.z + a2 * invd; o0.w = s0.w + a3 * invd;
            o1.x = s1.x + a4 * invd; o1.y = s1.y + a5 * invd;
            o1.z = s1.z + a6 * invd; o1.w = s1.w + a7 * invd;
            float* op = (float*)out + (size_t)w * NC + l * 8;
            *(float4*)op = o0;
            *(float4*)(op + 4) = o1;
        }
    }
}

extern "C" void kernel_launch(void* const* d_in, const int* in_sizes, int n_in,
                              void* d_out, int out_size, void* d_ws, size_t ws_size,
                              hipStream_t stream) {
    const float* x   = (const float*)d_in[0];
    const int*   src = (const int*)d_in[1];
    const int*   dst = (const int*)d_in[2];
    const float* Ws1 = (const float*)d_in[3];
    const float* Wn1 = (const float*)d_in[4];
    const float* b1  = (const float*)d_in[5];
    const float* Ws2 = (const float*)d_in[6];
    const float* Wn2 = (const float*)d_in[7];
    const float* b2  = (const float*)d_in[8];
    float* out = (float*)d_out;

    const size_t nd = (size_t)N_NODES * D;   // 12.8M elements
    // Aliasing (all kernels strictly sequential):
    //   buf0: xb (gemm1 in)  ==  h (agg1 out, gemm2 in)
    //   buf1: xs (gemm1 out) == tmp f32 (gemm2 out)
    //   buf2: y8 (gemm1 out) == z8 (gemm2 out)
    unsigned short* xb  = (unsigned short*)d_ws;          // 25.6 MB
    unsigned short* h   = xb;
    unsigned short* xs  = xb + nd;                        // 25.6 MB
    float*          tmp = (float*)xs;
    unsigned char*  y8  = (unsigned char*)(xs + nd);      // 12.8 MB
    unsigned char*  z8  = y8;
    int* dcount = (int*)(y8 + nd);                        // 0.4 MB
    int* csrp   = dcount + N_NODES;                       // 25.6 MB
    int* gcur   = csrp + (size_t)N_NODES * MAXDEG;        // (pad to 1024)
    int* bucketbuf = gcur + 1024;                         // 9.6 MB
    unsigned short* Wp1 = (unsigned short*)(bucketbuf + (size_t)NBUCK * BCAP); // 64 KB
    unsigned short* Wp2 = Wp1 + 32768;                    // 32 KB

    hipMemsetAsync(gcur, 0, NBUCK * sizeof(int), stream);

    split_k<<<NBLK_SPLIT, 256, 0, stream>>>(src, dst, gcur, bucketbuf);
    prep2<<<NBLK_CSR + NBLK_CVT + NBLK_PACK, 256, 0, stream>>>(
        x, gcur, bucketbuf, Ws1, Wn1, Ws2, Wn2, xb, dcount, csrp, Wp1, Wp2);

    const int gemm_blocks = (N_NODES + 63) / 64;          // 1563
    const int agg_blocks  = (N_NODES * 64 + 255) / 256;   // 25000

    // layer 1: [xs | y] = xb @ [Ws1+b1 | Wn1];  h = relu(xs + mean(y[nbrs]))
    gemm_dual<8, 8, true ><<<gemm_blocks, 256, 0, stream>>>(xb, Wp1, b1, xs, y8);
    agg_add<true ><<<agg_blocks, 256, 0, stream>>>(y8, csrp, dcount, xs, h);
    // layer 2: [tmp | z] = h @ [Ws2+b2 | Wn2]; out = tmp + mean(z[nbrs])
    gemm_dual<4, 4, false><<<gemm_blocks, 256, 0, stream>>>(h, Wp2, b2, tmp, z8);
    agg_add<false><<<agg_blocks, 256, 0, stream>>>(z8, csrp, dcount, tmp, out);
}

// Round 5
// 298.884 us; speedup vs baseline: 1.3133x; 1.0706x over previous
//
#include <hip/hip_runtime.h>

#define N_NODES 100000
#define N_EDGES 1600000
#define D 128      // D_IN == D_HID
#define D_OUT 64
#define MAXDEG 64  // Poisson(16); max over 100k nodes ~35. 64 = safe pow2.

// Bucketed CSR build (multisplit) — REQUIRED for scatter write locality
// (round-1 direct atomics: 16x write amplification, WRITE 45->134MB).
#define NBUCK 782          // buckets of 128 nodes
#define BSHIFT 7
#define BCAP  3072         // avg 2046 edges/bucket, ~10 sigma slack
#define NBLK_SPLIT 500
#define CHUNK 3200         // 500*3200 = 1.6M exact
#define NBLK_PACK 25       // 16 (Wp1) + 8 (Wp2) + 1 (zero pad rows)

typedef __attribute__((ext_vector_type(8))) short short8;   // 8 bf16 (4 VGPRs)
typedef __attribute__((ext_vector_type(4))) float floatx4;  // MFMA C/D
typedef __attribute__((ext_vector_type(2))) float floatx2;

__device__ inline unsigned short f2bf(float f) {   // RNE f32 -> bf16
    unsigned u = __builtin_bit_cast(unsigned, f);
    u = (u + 0x7fffu + ((u >> 16) & 1u)) >> 16;
    return (unsigned short)u;
}
__device__ inline float bf2f(unsigned u16) {
    return __builtin_bit_cast(float, u16 << 16);
}

// ---- pack W = [Wa | Wb] (N-concat, K=128) into MFMA B-frag order ----
__device__ inline void pack_ncat(const float* __restrict__ Wa, const float* __restrict__ Wb,
                                 int ncA, int ncB, unsigned short* __restrict__ out, int t) {
    int nnt = (ncA + ncB) >> 4;
    int lane = t & 63;
    int nt = (t >> 6) % nnt;
    int kt = t / (64 * nnt);                 // 0..3 (K=128)
    int col = nt * 16 + (lane & 15);
    int k0 = kt * 32 + ((lane >> 4) << 3);
    const float* W = (col < ncA) ? Wa : Wb;
    int nc = (col < ncA) ? ncA : ncB;
    int c  = (col < ncA) ? col : col - ncA;
    unsigned short* dstp = out + (size_t)((kt * nnt + nt) * 64 + lane) * 8;
    #pragma unroll
    for (int j = 0; j < 8; ++j)
        dstp[j] = f2bf(W[(size_t)(k0 + j) * nc + c]);
}

// ------- phase A: multisplit edges into 128-node buckets ∪ weight pack ∪ pad-zero --
__global__ __launch_bounds__(256) void split_pack(
        const int* __restrict__ src, const int* __restrict__ dst,
        int* __restrict__ gcur, int* __restrict__ bucketbuf,
        const float* __restrict__ Ws1, const float* __restrict__ Wn1,
        const float* __restrict__ Ws2, const float* __restrict__ Wn2,
        unsigned short* __restrict__ Wp1, unsigned short* __restrict__ Wp2,
        unsigned char* __restrict__ y8, unsigned char* __restrict__ z8) {
    __shared__ int cnt[NBUCK];
    __shared__ int base_s[NBUCK];
    __shared__ int dstc[CHUNK];    // cache dst chunk: read HBM once, not twice
    const int tid = threadIdx.x;
    const int b = blockIdx.x;
    if (b < NBLK_SPLIT) {
        const int e0 = b * CHUNK;
        for (int i = tid; i < NBUCK; i += 256) cnt[i] = 0;
        __syncthreads();
        for (int i = tid; i < CHUNK; i += 256) {
            int d = __builtin_nontemporal_load(dst + e0 + i);
            dstc[i] = d;
            atomicAdd(&cnt[d >> BSHIFT], 1);
        }
        __syncthreads();
        for (int i = tid; i < NBUCK; i += 256) {
            int c = cnt[i];
            base_s[i] = c ? atomicAdd(&gcur[i], c) : 0;
            cnt[i] = 0;   // reuse as per-block write cursor
        }
        __syncthreads();
        for (int i = tid; i < CHUNK; i += 256) {
            int d = dstc[i];
            int s = __builtin_nontemporal_load(src + e0 + i);
            int bk = d >> BSHIFT;
            int p = base_s[bk] + atomicAdd(&cnt[bk], 1);
            if (p < BCAP)   // statically impossible overflow; safety net
                bucketbuf[bk * BCAP + p] = ((d & 127) << 17) | s;
        }
    } else {
        int sub = b - NBLK_SPLIT;
        if (sub < 16)      pack_ncat(Ws1, Wn1, D, D, Wp1, sub * 256 + tid);
        else if (sub < 24) pack_ncat(Ws2, Wn2, D_OUT, D_OUT, Wp2, (sub - 16) * 256 + tid);
        else {
            // zero the sentinel pad rows (gathers of CSR padding land here)
            if (tid < 32)       ((unsigned*)(y8 + (size_t)N_NODES * 128))[tid] = 0;
            else if (tid < 48)  ((unsigned*)(z8 + (size_t)N_NODES * 64))[tid - 32] = 0;
        }
    }
}

// ------- phase B: per-bucket CSR build via LDS counters (no global atomics) -------
// Padding slots (up to next mult of 16) are filled with sentinel N_NODES, whose
// feature row is all-zero -> agg inner loop needs NO masking.
__global__ __launch_bounds__(256) void csr_build(
        const int* __restrict__ gcur, const int* __restrict__ bucketbuf,
        int* __restrict__ dcount, int* __restrict__ csrp) {
    __shared__ int lcnt[128];
    const int tid = threadIdx.x, b = blockIdx.x;
    if (tid < 128) lcnt[tid] = 0;
    __syncthreads();
    int m = gcur[b]; if (m > BCAP) m = BCAP;
    const int* __restrict__ buf = bucketbuf + b * BCAP;
    for (int i = tid; i < m; i += 256) {
        int v = buf[i];
        int dloc = (v >> 17) & 127, s = v & 0x1FFFF;
        int node = (b << BSHIFT) + dloc;
        int slot = atomicAdd(&lcnt[dloc], 1);
        if (slot < MAXDEG && node < N_NODES)
            csrp[((size_t)node << 6) + slot] = s;
    }
    __syncthreads();
    if (tid < 128) {
        int node = (b << BSHIFT) + tid;
        if (node < N_NODES) {
            int c = lcnt[tid]; if (c > MAXDEG) c = MAXDEG;
            dcount[node] = c;
            int cf = (c + 15) & ~15; if (cf > MAXDEG) cf = MAXDEG;
            int* row = csrp + ((size_t)node << 6);
            for (int k = c; k < cf; ++k) row[k] = N_NODES;   // sentinel -> zero row
        }
    }
}

// ------------- dual-output GEMM: [self+bias | nbr] = A @ [Ws | Wn], K=128 -------
// self (cols < NTA*16) gets +bias, written bf16 (L1) or f32 (L2).
// nbr  (cols >= NTA*16) written fp8 — the next gather's table. Mean-agg commutes
// with the linear map, so aggregating z = h@Wn AFTER the GEMM shrinks the
// layer-2 gather rows to 64B from an L2/L3-resident 6.4MB table.
// AF32: read A as f32 with in-register bf16 convert (kills the prep convert pass).
template<int NTA, int NTB, bool AF32, bool OUTA_BF16>
__global__ __launch_bounds__(256) void gemm_dual(
        const void* __restrict__ A, const unsigned short* __restrict__ Wp,
        const float* __restrict__ bias, void* __restrict__ OutA,
        unsigned char* __restrict__ OutB)
{
    const int NT = NTA + NTB;
    const int wave = threadIdx.x >> 6;
    const int lane = threadIdx.x & 63;
    const int q = lane >> 4, m = lane & 15;

    int row = blockIdx.x * 64 + wave * 16 + m;
    int rowc = (row < N_NODES) ? row : (N_NODES - 1);

    floatx4 acc[NT];
    #pragma unroll
    for (int nt = 0; nt < NT; ++nt) acc[nt] = (floatx4){0.f, 0.f, 0.f, 0.f};

    #pragma unroll
    for (int kt = 0; kt < 4; ++kt) {
        short8 af;
        if (AF32) {
            const float* xr = (const float*)A + (size_t)rowc * D + kt * 32 + q * 8;
            float4 f0 = *(const float4*)xr;
            float4 f1 = *(const float4*)(xr + 4);
            af[0] = (short)f2bf(f0.x); af[1] = (short)f2bf(f0.y);
            af[2] = (short)f2bf(f0.z); af[3] = (short)f2bf(f0.w);
            af[4] = (short)f2bf(f1.x); af[5] = (short)f2bf(f1.y);
            af[6] = (short)f2bf(f1.z); af[7] = (short)f2bf(f1.w);
        } else {
            af = *(const short8*)((const unsigned short*)A +
                                  (size_t)rowc * D + kt * 32 + q * 8);
        }
        #pragma unroll
        for (int nt = 0; nt < NT; ++nt) {
            short8 bf = *(const short8*)(Wp + (size_t)((kt * NT + nt) * 64 + lane) * 8);
            acc[nt] = __builtin_amdgcn_mfma_f32_16x16x32_bf16(af, bf, acc[nt], 0, 0, 0);
        }
    }

    const int orow_base = blockIdx.x * 64 + wave * 16 + q * 4;
    #pragma unroll
    for (int nt = 0; nt < NT; ++nt) {
        float bv = (nt < NTA) ? bias[nt * 16 + m] : 0.f;
        #pragma unroll
        for (int i = 0; i < 4; ++i) {
            int orow = orow_base + i;
            if (orow < N_NODES) {
                float v = acc[nt][i];
                if (nt < NTA) {
                    v += bv;
                    if (OUTA_BF16)
                        ((unsigned short*)OutA)[(size_t)orow * (NTA * 16) + nt * 16 + m] = f2bf(v);
                    else
                        ((float*)OutA)[(size_t)orow * (NTA * 16) + nt * 16 + m] = v;
                } else {
                    int pk = __builtin_amdgcn_cvt_pk_fp8_f32(v, v, 0, false);
                    OutB[(size_t)orow * (NTB * 16) + (nt - NTA) * 16 + m] =
                        (unsigned char)(pk & 0xff);
                }
            }
        }
    }
}

// ---------- mean-agg + self-add: one wave per node, 4B/lane dword gathers -------
// L1: 32 lanes/edge (128B rows), fold = ONE shfl step. L2: 16 lanes/edge (64B),
// fold = two steps. floatx2 accumulators -> packed adds. Inner loop is fully
// unconditional: CSR padding points at the zeroed sentinel row.
template<bool L1>
__global__ __launch_bounds__(256) void agg_add(
        const unsigned char* __restrict__ feat, const int* __restrict__ csrp,
        const int* __restrict__ dcount, const void* __restrict__ self,
        void* __restrict__ out)
{
    const int LPE = L1 ? 32 : 16;      // lanes per edge (4B/lane)
    const int EPG = 64 / LPE;          // edges per load-group: 2 (L1), 4 (L2)
    const int FSH = L1 ? 7 : 6;        // log2(row bytes)
    const int NC  = L1 ? 128 : 64;     // columns

    int w = (blockIdx.x * 256 + threadIdx.x) >> 6;
    int lane = threadIdx.x & 63;
    if (w >= N_NODES) return;
    int dg = __builtin_amdgcn_readfirstlane(dcount[w]);
    const int g = lane / LPE;          // edge slot within group
    const int l = lane % LPE;          // dword chunk (4 columns)
    int idxv = csrp[((size_t)w << 6) + lane];   // whole padded row, one load

    floatx2 ac0 = (floatx2){0.f, 0.f};
    floatx2 ac1 = (floatx2){0.f, 0.f};
    for (int j = 0; j < dg; j += 16) {
        #pragma unroll
        for (int u = 0; u < 16 / EPG; ++u) {
            int s = __shfl(idxv, j + u * EPG + g);
            unsigned v = *(const unsigned*)(feat + ((size_t)s << FSH) + (l << 2));
            ac0 += __builtin_amdgcn_cvt_pk_f32_fp8(v, false);
            ac1 += __builtin_amdgcn_cvt_pk_f32_fp8(v, true);
        }
    }
    // fold edge-slot groups (lanes sharing l)
    #pragma unroll
    for (int delta = 32; delta >= LPE; delta >>= 1) {
        ac0.x += __shfl_down(ac0.x, delta); ac0.y += __shfl_down(ac0.y, delta);
        ac1.x += __shfl_down(ac1.x, delta); ac1.y += __shfl_down(ac1.y, delta);
    }
    if (g == 0) {                      // lanes 0..LPE-1 hold 4-col sums
        float invd = (dg > 0) ? 1.0f / (float)dg : 1.0f;
        if (L1) {                      // self bf16, out bf16 + ReLU
            uint2 sv = *(const uint2*)((const unsigned short*)self + (size_t)w * NC + l * 4);
            float h0 = bf2f(sv.x & 0xffffu)  + ac0.x * invd;
            float h1 = bf2f(sv.x >> 16)      + ac0.y * invd;
            float h2 = bf2f(sv.y & 0xffffu)  + ac1.x * invd;
            float h3 = bf2f(sv.y >> 16)      + ac1.y * invd;
            h0 = fmaxf(h0, 0.f); h1 = fmaxf(h1, 0.f);
            h2 = fmaxf(h2, 0.f); h3 = fmaxf(h3, 0.f);
            uint2 pv;
            pv.x = (unsigned)f2bf(h0) | ((unsigned)f2bf(h1) << 16);
            pv.y = (unsigned)f2bf(h2) | ((unsigned)f2bf(h3) << 16);
            *(uint2*)((unsigned short*)out + (size_t)w * NC + l * 4) = pv;
        } else {                       // self f32, out f32
            const float* sp = (const float*)self + (size_t)w * NC + l * 4;
            float4 s0 = *(const float4*)sp;
            float4 o;
            o.x = s0.x + ac0.x * invd; o.y = s0.y + ac0.y * invd;
            o.z = s0.z + ac1.x * invd; o.w = s0.w + ac1.y * invd;
            *(float4*)((float*)out + (size_t)w * NC + l * 4) = o;
        }
    }
}

extern "C" void kernel_launch(void* const* d_in, const int* in_sizes, int n_in,
                              void* d_out, int out_size, void* d_ws, size_t ws_size,
                              hipStream_t stream) {
    const float* x   = (const float*)d_in[0];
    const int*   src = (const int*)d_in[1];
    const int*   dst = (const int*)d_in[2];
    const float* Ws1 = (const float*)d_in[3];
    const float* Wn1 = (const float*)d_in[4];
    const float* b1  = (const float*)d_in[5];
    const float* Ws2 = (const float*)d_in[6];
    const float* Wn2 = (const float*)d_in[7];
    const float* b2  = (const float*)d_in[8];
    float* out = (float*)d_out;

    const size_t nd = (size_t)N_NODES * D;   // 12.8M elements
    unsigned short* h   = (unsigned short*)d_ws;          // bf16 hidden   25.6 MB
    unsigned short* xs  = h + nd;                         // bf16 self (L1) 25.6 MB
    float*          tmp = (float*)xs;                     // f32 self (L2), aliased
    unsigned char*  y8  = (unsigned char*)(xs + nd);      // fp8 y + pad   12.8 MB
    unsigned char*  z8  = y8 + (size_t)(N_NODES + 1) * D; // fp8 z + pad    6.4 MB
    int* dcount = (int*)(z8 + (size_t)(N_NODES + 1) * D_OUT);
    int* csrp   = dcount + N_NODES;                       // padded CSR    25.6 MB
    int* gcur   = csrp + (size_t)N_NODES * MAXDEG;        // (pad to 1024)
    int* bucketbuf = gcur + 1024;                         // bucket edges   9.6 MB
    unsigned short* Wp1 = (unsigned short*)(bucketbuf + (size_t)NBUCK * BCAP); // 64 KB
    unsigned short* Wp2 = Wp1 + 32768;                    // 32 KB

    hipMemsetAsync(gcur, 0, NBUCK * sizeof(int), stream);

    split_pack<<<NBLK_SPLIT + NBLK_PACK, 256, 0, stream>>>(
        src, dst, gcur, bucketbuf, Ws1, Wn1, Ws2, Wn2, Wp1, Wp2, y8, z8);
    csr_build<<<NBUCK, 256, 0, stream>>>(gcur, bucketbuf, dcount, csrp);

    const int gemm_blocks = (N_NODES + 63) / 64;          // 1563
    const int agg_blocks  = (N_NODES * 64 + 255) / 256;   // 25000

    // layer 1: [xs | y] = bf16(x) @ [Ws1+b1 | Wn1];  h = relu(xs + mean(y[nbrs]))
    gemm_dual<8, 8, true,  true ><<<gemm_blocks, 256, 0, stream>>>(x, Wp1, b1, xs, y8);
    agg_add<true ><<<agg_blocks, 256, 0, stream>>>(y8, csrp, dcount, xs, h);
    // layer 2: [tmp | z] = h @ [Ws2+b2 | Wn2]; out = tmp + mean(z[nbrs])
    gemm_dual<4, 4, false, false><<<gemm_blocks, 256, 0, stream>>>(h, Wp2, b2, tmp, z8);
    agg_add<false><<<agg_blocks, 256, 0, stream>>>(z8, csrp, dcount, tmp, out);
}

// Round 6
// 286.679 us; speedup vs baseline: 1.3693x; 1.0426x over previous
//
#include <hip/hip_runtime.h>

#define N_NODES 100000
#define N_EDGES 1600000
#define D 128      // D_IN == D_HID
#define D_OUT 64
#define MAXDEG 64  // Poisson(16); max over 100k nodes ~35. 64 = safe pow2.

// Bucketed CSR build (multisplit) — REQUIRED for scatter write locality
// (round-1 direct atomics: 16x write amplification, WRITE 45->134MB).
#define NBUCK 782          // buckets of 128 nodes
#define BSHIFT 7
#define BCAP  3072         // avg 2046 edges/bucket, ~10 sigma slack
#define NBLK_SPLIT 500
#define CHUNK 3200         // 500*3200 = 1.6M exact
#define NBLK_PACK 25       // 16 (Wp1) + 8 (Wp2) + 1 (zero pad rows)

typedef __attribute__((ext_vector_type(8))) short short8;   // 8 bf16 (4 VGPRs)
typedef __attribute__((ext_vector_type(4))) float floatx4;  // MFMA C/D
typedef __attribute__((ext_vector_type(2))) float floatx2;

__device__ inline unsigned short f2bf(float f) {   // RNE f32 -> bf16
    unsigned u = __builtin_bit_cast(unsigned, f);
    u = (u + 0x7fffu + ((u >> 16) & 1u)) >> 16;
    return (unsigned short)u;
}
__device__ inline float bf2f(unsigned u16) {
    return __builtin_bit_cast(float, u16 << 16);
}

// ---- pack W = [Wa | Wb] (N-concat, K=128) into MFMA B-frag order ----
// KPERM: permute K-rows to consume an interleave-stored A (see gemm_dual ILV):
// packed K-position k holds original row ((k&7)<<4)|(k>>3).
template<bool KPERM>
__device__ inline void pack_ncat(const float* __restrict__ Wa, const float* __restrict__ Wb,
                                 int ncA, int ncB, unsigned short* __restrict__ out, int t) {
    int nnt = (ncA + ncB) >> 4;
    int lane = t & 63;
    int nt = (t >> 6) % nnt;
    int kt = t / (64 * nnt);                 // 0..3 (K=128)
    int col = nt * 16 + (lane & 15);
    int k0 = kt * 32 + ((lane >> 4) << 3);
    const float* W = (col < ncA) ? Wa : Wb;
    int nc = (col < ncA) ? ncA : ncB;
    int c  = (col < ncA) ? col : col - ncA;
    unsigned short* dstp = out + (size_t)((kt * nnt + nt) * 64 + lane) * 8;
    #pragma unroll
    for (int j = 0; j < 8; ++j) {
        int k = k0 + j;
        int kr = KPERM ? (((k & 7) << 4) | (k >> 3)) : k;
        dstp[j] = f2bf(W[(size_t)kr * nc + c]);
    }
}

// ------- phase A: multisplit edges into 128-node buckets ∪ weight pack ∪ pad-zero --
__global__ __launch_bounds__(256) void split_pack(
        const int* __restrict__ src, const int* __restrict__ dst,
        int* __restrict__ gcur, int* __restrict__ bucketbuf,
        const float* __restrict__ Ws1, const float* __restrict__ Wn1,
        const float* __restrict__ Ws2, const float* __restrict__ Wn2,
        unsigned short* __restrict__ Wp1, unsigned short* __restrict__ Wp2,
        unsigned char* __restrict__ y8, unsigned char* __restrict__ z8) {
    __shared__ int cnt[NBUCK];
    __shared__ int base_s[NBUCK];
    __shared__ int dstc[CHUNK];    // cache dst chunk: read HBM once, not twice
    const int tid = threadIdx.x;
    const int b = blockIdx.x;
    if (b < NBLK_SPLIT) {
        const int e0 = b * CHUNK;
        for (int i = tid; i < NBUCK; i += 256) cnt[i] = 0;
        __syncthreads();
        for (int i = tid; i < CHUNK; i += 256) {
            int d = __builtin_nontemporal_load(dst + e0 + i);
            dstc[i] = d;
            atomicAdd(&cnt[d >> BSHIFT], 1);
        }
        __syncthreads();
        for (int i = tid; i < NBUCK; i += 256) {
            int c = cnt[i];
            base_s[i] = c ? atomicAdd(&gcur[i], c) : 0;
            cnt[i] = 0;   // reuse as per-block write cursor
        }
        __syncthreads();
        for (int i = tid; i < CHUNK; i += 256) {
            int d = dstc[i];
            int s = __builtin_nontemporal_load(src + e0 + i);
            int bk = d >> BSHIFT;
            int p = base_s[bk] + atomicAdd(&cnt[bk], 1);
            if (p < BCAP)   // statically impossible overflow; safety net
                bucketbuf[bk * BCAP + p] = ((d & 127) << 17) | s;
        }
    } else {
        int sub = b - NBLK_SPLIT;
        if (sub < 16)      pack_ncat<false>(Ws1, Wn1, D, D, Wp1, sub * 256 + tid);
        else if (sub < 24) pack_ncat<true >(Ws2, Wn2, D_OUT, D_OUT, Wp2, (sub - 16) * 256 + tid);
        else {
            // zero the sentinel pad rows (gathers of CSR padding land here)
            if (tid < 32)       ((unsigned*)(y8 + (size_t)N_NODES * 128))[tid] = 0;
            else if (tid < 48)  ((unsigned*)(z8 + (size_t)N_NODES * 64))[tid - 32] = 0;
        }
    }
}

// ------- phase B: per-bucket CSR build via LDS counters (no global atomics) -------
// Padding slots (up to next mult of 16) are filled with sentinel N_NODES, whose
// feature row is all-zero -> agg inner loop needs NO masking.
__global__ __launch_bounds__(256) void csr_build(
        const int* __restrict__ gcur, const int* __restrict__ bucketbuf,
        int* __restrict__ dcount, int* __restrict__ csrp) {
    __shared__ int lcnt[128];
    const int tid = threadIdx.x, b = blockIdx.x;
    if (tid < 128) lcnt[tid] = 0;
    __syncthreads();
    int m = gcur[b]; if (m > BCAP) m = BCAP;
    const int* __restrict__ buf = bucketbuf + b * BCAP;
    for (int i = tid; i < m; i += 256) {
        int v = buf[i];
        int dloc = (v >> 17) & 127, s = v & 0x1FFFF;
        int node = (b << BSHIFT) + dloc;
        int slot = atomicAdd(&lcnt[dloc], 1);
        if (slot < MAXDEG && node < N_NODES)
            csrp[((size_t)node << 6) + slot] = s;
    }
    __syncthreads();
    if (tid < 128) {
        int node = (b << BSHIFT) + tid;
        if (node < N_NODES) {
            int c = lcnt[tid]; if (c > MAXDEG) c = MAXDEG;
            dcount[node] = c;
            int cf = (c + 15) & ~15; if (cf > MAXDEG) cf = MAXDEG;
            int* row = csrp + ((size_t)node << 6);
            for (int k = c; k < cf; ++k) row[k] = N_NODES;   // sentinel -> zero row
        }
    }
}

// ------------- dual-output GEMM: [self+bias | nbr] = A @ [Ws | Wn], K=128 -------
// ILV (layer 1): store acc[nt] (lane m) at COLUMN POSITION m*8+nt instead of
// nt*16+m -> each lane's 8 outputs are contiguous: ONE 16B bf16 store + ONE 8B
// fp8 store per output row (8 stores/lane vs 64). Downstream is positional
// (agg) and gemm2's Wp2 is K-row-permuted to match (pack_ncat<KPERM>), so the
// interleave costs nothing anywhere else. Layer 2 keeps identity order (its
// outputs feed the final result).
template<int NTA, int NTB, bool AF32, bool OUTA_BF16, bool ILV>
__global__ __launch_bounds__(256) void gemm_dual(
        const void* __restrict__ A, const unsigned short* __restrict__ Wp,
        const float* __restrict__ bias, void* __restrict__ OutA,
        unsigned char* __restrict__ OutB)
{
    const int NT = NTA + NTB;
    const int wave = threadIdx.x >> 6;
    const int lane = threadIdx.x & 63;
    const int q = lane >> 4, m = lane & 15;

    int row = blockIdx.x * 64 + wave * 16 + m;
    int rowc = (row < N_NODES) ? row : (N_NODES - 1);

    floatx4 acc[NT];
    #pragma unroll
    for (int nt = 0; nt < NT; ++nt) acc[nt] = (floatx4){0.f, 0.f, 0.f, 0.f};

    #pragma unroll
    for (int kt = 0; kt < 4; ++kt) {
        short8 af;
        if (AF32) {
            const float* xr = (const float*)A + (size_t)rowc * D + kt * 32 + q * 8;
            float4 f0 = *(const float4*)xr;
            float4 f1 = *(const float4*)(xr + 4);
            af[0] = (short)f2bf(f0.x); af[1] = (short)f2bf(f0.y);
            af[2] = (short)f2bf(f0.z); af[3] = (short)f2bf(f0.w);
            af[4] = (short)f2bf(f1.x); af[5] = (short)f2bf(f1.y);
            af[6] = (short)f2bf(f1.z); af[7] = (short)f2bf(f1.w);
        } else {
            af = *(const short8*)((const unsigned short*)A +
                                  (size_t)rowc * D + kt * 32 + q * 8);
        }
        #pragma unroll
        for (int nt = 0; nt < NT; ++nt) {
            short8 bf = *(const short8*)(Wp + (size_t)((kt * NT + nt) * 64 + lane) * 8);
            acc[nt] = __builtin_amdgcn_mfma_f32_16x16x32_bf16(af, bf, acc[nt], 0, 0, 0);
        }
    }

    const int orow_base = blockIdx.x * 64 + wave * 16 + q * 4;
    if (ILV) {
        // NTA==8, NTB==8 assumed. Position m*8+nt holds original col nt*16+m.
        float bv[8];
        #pragma unroll
        for (int nt = 0; nt < 8; ++nt) bv[nt] = bias[nt * 16 + m];
        #pragma unroll
        for (int i = 0; i < 4; ++i) {
            int orow = orow_base + i;
            if (orow < N_NODES) {
                unsigned w[4];
                #pragma unroll
                for (int t = 0; t < 4; ++t) {
                    float v0 = acc[2 * t][i]     + bv[2 * t];
                    float v1 = acc[2 * t + 1][i] + bv[2 * t + 1];
                    w[t] = (unsigned)f2bf(v0) | ((unsigned)f2bf(v1) << 16);
                }
                uint4 pv; pv.x = w[0]; pv.y = w[1]; pv.z = w[2]; pv.w = w[3];
                *(uint4*)((unsigned short*)OutA + (size_t)orow * 128 + m * 8) = pv;
                int pk0 = __builtin_amdgcn_cvt_pk_fp8_f32(acc[8][i],  acc[9][i],  0,   false);
                pk0     = __builtin_amdgcn_cvt_pk_fp8_f32(acc[10][i], acc[11][i], pk0, true);
                int pk1 = __builtin_amdgcn_cvt_pk_fp8_f32(acc[12][i], acc[13][i], 0,   false);
                pk1     = __builtin_amdgcn_cvt_pk_fp8_f32(acc[14][i], acc[15][i], pk1, true);
                uint2 v8; v8.x = (unsigned)pk0; v8.y = (unsigned)pk1;
                *(uint2*)(OutB + (size_t)orow * 128 + m * 8) = v8;
            }
        }
    } else {
        #pragma unroll
        for (int nt = 0; nt < NT; ++nt) {
            float bv = (nt < NTA) ? bias[nt * 16 + m] : 0.f;
            #pragma unroll
            for (int i = 0; i < 4; ++i) {
                int orow = orow_base + i;
                if (orow < N_NODES) {
                    float v = acc[nt][i];
                    if (nt < NTA) {
                        v += bv;
                        if (OUTA_BF16)
                            ((unsigned short*)OutA)[(size_t)orow * (NTA * 16) + nt * 16 + m] = f2bf(v);
                        else
                            ((float*)OutA)[(size_t)orow * (NTA * 16) + nt * 16 + m] = v;
                    } else {
                        int pk = __builtin_amdgcn_cvt_pk_fp8_f32(v, v, 0, false);
                        OutB[(size_t)orow * (NTB * 16) + (nt - NTA) * 16 + m] =
                            (unsigned char)(pk & 0xff);
                    }
                }
            }
        }
    }
}

// ---------- mean-agg + self-add: one wave per node, 4B/lane dword gathers -------
// L1: 32 lanes/edge (128B rows), fold = ONE shfl step. L2: 16 lanes/edge (64B),
// fold = two steps. floatx2 accumulators -> packed adds. Inner loop is fully
// unconditional: CSR padding points at the zeroed sentinel row. Purely
// positional -> works identically on interleave-permuted columns.
template<bool L1>
__global__ __launch_bounds__(256) void agg_add(
        const unsigned char* __restrict__ feat, const int* __restrict__ csrp,
        const int* __restrict__ dcount, const void* __restrict__ self,
        void* __restrict__ out)
{
    const int LPE = L1 ? 32 : 16;      // lanes per edge (4B/lane)
    const int EPG = 64 / LPE;          // edges per load-group: 2 (L1), 4 (L2)
    const int FSH = L1 ? 7 : 6;        // log2(row bytes)
    const int NC  = L1 ? 128 : 64;     // columns

    int w = (blockIdx.x * 256 + threadIdx.x) >> 6;
    int lane = threadIdx.x & 63;
    if (w >= N_NODES) return;
    int dg = __builtin_amdgcn_readfirstlane(dcount[w]);
    const int g = lane / LPE;          // edge slot within group
    const int l = lane % LPE;          // dword chunk (4 columns)
    int idxv = csrp[((size_t)w << 6) + lane];   // whole padded row, one load

    floatx2 ac0 = (floatx2){0.f, 0.f};
    floatx2 ac1 = (floatx2){0.f, 0.f};
    for (int j = 0; j < dg; j += 16) {
        #pragma unroll
        for (int u = 0; u < 16 / EPG; ++u) {
            int s = __shfl(idxv, j + u * EPG + g);
            unsigned v = *(const unsigned*)(feat + ((size_t)s << FSH) + (l << 2));
            ac0 += __builtin_amdgcn_cvt_pk_f32_fp8(v, false);
            ac1 += __builtin_amdgcn_cvt_pk_f32_fp8(v, true);
        }
    }
    // fold edge-slot groups (lanes sharing l)
    #pragma unroll
    for (int delta = 32; delta >= LPE; delta >>= 1) {
        ac0.x += __shfl_down(ac0.x, delta); ac0.y += __shfl_down(ac0.y, delta);
        ac1.x += __shfl_down(ac1.x, delta); ac1.y += __shfl_down(ac1.y, delta);
    }
    if (g == 0) {                      // lanes 0..LPE-1 hold 4-col sums
        float invd = (dg > 0) ? 1.0f / (float)dg : 1.0f;
        if (L1) {                      // self bf16, out bf16 + ReLU
            uint2 sv = *(const uint2*)((const unsigned short*)self + (size_t)w * NC + l * 4);
            float h0 = bf2f(sv.x & 0xffffu)  + ac0.x * invd;
            float h1 = bf2f(sv.x >> 16)      + ac0.y * invd;
            float h2 = bf2f(sv.y & 0xffffu)  + ac1.x * invd;
            float h3 = bf2f(sv.y >> 16)      + ac1.y * invd;
            h0 = fmaxf(h0, 0.f); h1 = fmaxf(h1, 0.f);
            h2 = fmaxf(h2, 0.f); h3 = fmaxf(h3, 0.f);
            uint2 pv;
            pv.x = (unsigned)f2bf(h0) | ((unsigned)f2bf(h1) << 16);
            pv.y = (unsigned)f2bf(h2) | ((unsigned)f2bf(h3) << 16);
            *(uint2*)((unsigned short*)out + (size_t)w * NC + l * 4) = pv;
        } else {                       // self f32, out f32
            const float* sp = (const float*)self + (size_t)w * NC + l * 4;
            float4 s0 = *(const float4*)sp;
            float4 o;
            o.x = s0.x + ac0.x * invd; o.y = s0.y + ac0.y * invd;
            o.z = s0.z + ac1.x * invd; o.w = s0.w + ac1.y * invd;
            *(float4*)((float*)out + (size_t)w * NC + l * 4) = o;
        }
    }
}

extern "C" void kernel_launch(void* const* d_in, const int* in_sizes, int n_in,
                              void* d_out, int out_size, void* d_ws, size_t ws_size,
                              hipStream_t stream) {
    const float* x   = (const float*)d_in[0];
    const int*   src = (const int*)d_in[1];
    const int*   dst = (const int*)d_in[2];
    const float* Ws1 = (const float*)d_in[3];
    const float* Wn1 = (const float*)d_in[4];
    const float* b1  = (const float*)d_in[5];
    const float* Ws2 = (const float*)d_in[6];
    const float* Wn2 = (const float*)d_in[7];
    const float* b2  = (const float*)d_in[8];
    float* out = (float*)d_out;

    const size_t nd = (size_t)N_NODES * D;   // 12.8M elements
    unsigned short* h   = (unsigned short*)d_ws;          // bf16 hidden   25.6 MB
    unsigned short* xs  = h + nd;                         // bf16 self (L1) 25.6 MB
    float*          tmp = (float*)xs;                     // f32 self (L2), aliased
    unsigned char*  y8  = (unsigned char*)(xs + nd);      // fp8 y + pad   12.8 MB
    unsigned char*  z8  = y8 + (size_t)(N_NODES + 1) * D; // fp8 z + pad    6.4 MB
    int* dcount = (int*)(z8 + (size_t)(N_NODES + 1) * D_OUT);
    int* csrp   = dcount + N_NODES;                       // padded CSR    25.6 MB
    int* gcur   = csrp + (size_t)N_NODES * MAXDEG;        // (pad to 1024)
    int* bucketbuf = gcur + 1024;                         // bucket edges   9.6 MB
    unsigned short* Wp1 = (unsigned short*)(bucketbuf + (size_t)NBUCK * BCAP); // 64 KB
    unsigned short* Wp2 = Wp1 + 32768;                    // 32 KB

    hipMemsetAsync(gcur, 0, NBUCK * sizeof(int), stream);

    split_pack<<<NBLK_SPLIT + NBLK_PACK, 256, 0, stream>>>(
        src, dst, gcur, bucketbuf, Ws1, Wn1, Ws2, Wn2, Wp1, Wp2, y8, z8);
    csr_build<<<NBUCK, 256, 0, stream>>>(gcur, bucketbuf, dcount, csrp);

    const int gemm_blocks = (N_NODES + 63) / 64;          // 1563
    const int agg_blocks  = (N_NODES * 64 + 255) / 256;   // 25000

    // layer 1 (interleaved cols): [xs | y] = bf16(x) @ [Ws1+b1 | Wn1]
    gemm_dual<8, 8, true,  true,  true ><<<gemm_blocks, 256, 0, stream>>>(x, Wp1, b1, xs, y8);
    agg_add<true ><<<agg_blocks, 256, 0, stream>>>(y8, csrp, dcount, xs, h);
    // layer 2 (identity cols; Wp2 K-rows permuted to consume interleaved h)
    gemm_dual<4, 4, false, false, false><<<gemm_blocks, 256, 0, stream>>>(h, Wp2, b2, tmp, z8);
    agg_add<false><<<agg_blocks, 256, 0, stream>>>(z8, csrp, dcount, tmp, out);
}

// Round 7
// 274.689 us; speedup vs baseline: 1.4290x; 1.0436x over previous
//
#include <hip/hip_runtime.h>

#define N_NODES 100000
#define N_EDGES 1600000
#define D 128      // D_IN == D_HID
#define D_OUT 64
#define MAXDEG 64  // Poisson(16); max over 100k nodes ~35. 64 = safe pow2.

// Bucketed CSR build (multisplit) — REQUIRED for scatter write locality
// (round-1 direct atomics: 16x write amplification, WRITE 45->134MB).
#define NBUCK 782          // buckets of 128 nodes
#define BSHIFT 7
#define BCAP  3072         // avg 2046 edges/bucket, ~10 sigma slack
#define NBLK_SPLIT 500
#define CHUNK 3200         // 500*3200 = 1.6M exact
#define NBLK_PACK 25       // 16 (Wp1) + 8 (Wp2) + 1 (zero pad rows)
#define GEMM_BLOCKS 1563   // ceil(100000/64)

typedef __attribute__((ext_vector_type(8))) short short8;   // 8 bf16 (4 VGPRs)
typedef __attribute__((ext_vector_type(4))) float floatx4;  // MFMA C/D
typedef __attribute__((ext_vector_type(2))) float floatx2;

__device__ inline unsigned short f2bf(float f) {   // RNE f32 -> bf16
    unsigned u = __builtin_bit_cast(unsigned, f);
    u = (u + 0x7fffu + ((u >> 16) & 1u)) >> 16;
    return (unsigned short)u;
}
__device__ inline float bf2f(unsigned u16) {
    return __builtin_bit_cast(float, u16 << 16);
}

// ---- pack W = [Wa | Wb] (N-concat, K=128) into MFMA B-frag order ----
// KPERM: permute K-rows to consume an interleave-stored A (gemm ILV=1 output):
// packed K-position k holds original row ((k&7)<<4)|(k>>3).
template<bool KPERM>
__device__ inline void pack_ncat(const float* __restrict__ Wa, const float* __restrict__ Wb,
                                 int ncA, int ncB, unsigned short* __restrict__ out, int t) {
    int nnt = (ncA + ncB) >> 4;
    int lane = t & 63;
    int nt = (t >> 6) % nnt;
    int kt = t / (64 * nnt);                 // 0..3 (K=128)
    int col = nt * 16 + (lane & 15);
    int k0 = kt * 32 + ((lane >> 4) << 3);
    const float* W = (col < ncA) ? Wa : Wb;
    int nc = (col < ncA) ? ncA : ncB;
    int c  = (col < ncA) ? col : col - ncA;
    unsigned short* dstp = out + (size_t)((kt * nnt + nt) * 64 + lane) * 8;
    #pragma unroll
    for (int j = 0; j < 8; ++j) {
        int k = k0 + j;
        int kr = KPERM ? (((k & 7) << 4) | (k >> 3)) : k;
        dstp[j] = f2bf(W[(size_t)kr * nc + c]);
    }
}

// ------- phase A: multisplit edges into 128-node buckets ∪ weight pack ∪ pad-zero --
__global__ __launch_bounds__(256) void split_pack(
        const int* __restrict__ src, const int* __restrict__ dst,
        int* __restrict__ gcur, int* __restrict__ bucketbuf,
        const float* __restrict__ Ws1, const float* __restrict__ Wn1,
        const float* __restrict__ Ws2, const float* __restrict__ Wn2,
        unsigned short* __restrict__ Wp1, unsigned short* __restrict__ Wp2,
        unsigned char* __restrict__ y8, unsigned char* __restrict__ z8) {
    __shared__ int cnt[NBUCK];
    __shared__ int base_s[NBUCK];
    __shared__ int dstc[CHUNK];    // cache dst chunk: read HBM once, not twice
    const int tid = threadIdx.x;
    const int b = blockIdx.x;
    if (b < NBLK_SPLIT) {
        const int e0 = b * CHUNK;
        for (int i = tid; i < NBUCK; i += 256) cnt[i] = 0;
        __syncthreads();
        for (int i = tid; i < CHUNK; i += 256) {
            int d = __builtin_nontemporal_load(dst + e0 + i);
            dstc[i] = d;
            atomicAdd(&cnt[d >> BSHIFT], 1);
        }
        __syncthreads();
        for (int i = tid; i < NBUCK; i += 256) {
            int c = cnt[i];
            base_s[i] = c ? atomicAdd(&gcur[i], c) : 0;
            cnt[i] = 0;   // reuse as per-block write cursor
        }
        __syncthreads();
        for (int i = tid; i < CHUNK; i += 256) {
            int d = dstc[i];
            int s = __builtin_nontemporal_load(src + e0 + i);
            int bk = d >> BSHIFT;
            int p = base_s[bk] + atomicAdd(&cnt[bk], 1);
            if (p < BCAP)   // statically impossible overflow; safety net
                bucketbuf[bk * BCAP + p] = ((d & 127) << 17) | s;
        }
    } else {
        int sub = b - NBLK_SPLIT;
        if (sub < 16)      pack_ncat<false>(Ws1, Wn1, D, D, Wp1, sub * 256 + tid);
        else if (sub < 24) pack_ncat<true >(Ws2, Wn2, D_OUT, D_OUT, Wp2, (sub - 16) * 256 + tid);
        else {
            // zero the sentinel pad rows (gathers of CSR padding land here)
            if (tid < 32)       ((unsigned*)(y8 + (size_t)N_NODES * 128))[tid] = 0;
            else if (tid < 48)  ((unsigned*)(z8 + (size_t)N_NODES * 64))[tid - 32] = 0;
        }
    }
}

// --------------- shared GEMM body: [self+bias | nbr] = A @ [Ws | Wn], K=128 -----
// ILV=1 (layer 1, NTA=NTB=8): store position m*8+nt <- col nt*16+m; one 16B bf16
//   + one 8B fp8 store per row per lane. Wp2 is K-row-permuted to consume it.
// ILV=2 (layer 2, NTA=NTB=4): store position m*4+nt <- col nt*16+m; one 16B f32
//   + one 4B fp8 store. agg_add<L2> un-permutes at its final coalesced write.
template<int NTA, int NTB, bool AF32, int ILV>
__device__ inline void gemm_body(int bid,
        const void* __restrict__ A, const unsigned short* __restrict__ Wp,
        const float* __restrict__ bias, void* __restrict__ OutA,
        unsigned char* __restrict__ OutB, int tid)
{
    const int NT = NTA + NTB;
    const int wave = tid >> 6;
    const int lane = tid & 63;
    const int q = lane >> 4, m = lane & 15;

    int row = bid * 64 + wave * 16 + m;
    int rowc = (row < N_NODES) ? row : (N_NODES - 1);

    floatx4 acc[NT];
    #pragma unroll
    for (int nt = 0; nt < NT; ++nt) acc[nt] = (floatx4){0.f, 0.f, 0.f, 0.f};

    #pragma unroll
    for (int kt = 0; kt < 4; ++kt) {
        short8 af;
        if (AF32) {
            const float* xr = (const float*)A + (size_t)rowc * D + kt * 32 + q * 8;
            float4 f0 = *(const float4*)xr;
            float4 f1 = *(const float4*)(xr + 4);
            af[0] = (short)f2bf(f0.x); af[1] = (short)f2bf(f0.y);
            af[2] = (short)f2bf(f0.z); af[3] = (short)f2bf(f0.w);
            af[4] = (short)f2bf(f1.x); af[5] = (short)f2bf(f1.y);
            af[6] = (short)f2bf(f1.z); af[7] = (short)f2bf(f1.w);
        } else {
            af = *(const short8*)((const unsigned short*)A +
                                  (size_t)rowc * D + kt * 32 + q * 8);
        }
        #pragma unroll
        for (int nt = 0; nt < NT; ++nt) {
            short8 bf = *(const short8*)(Wp + (size_t)((kt * NT + nt) * 64 + lane) * 8);
            acc[nt] = __builtin_amdgcn_mfma_f32_16x16x32_bf16(af, bf, acc[nt], 0, 0, 0);
        }
    }

    const int orow_base = bid * 64 + wave * 16 + q * 4;
    if (ILV == 1) {
        float bv[8];
        #pragma unroll
        for (int nt = 0; nt < 8; ++nt) bv[nt] = bias[nt * 16 + m];
        #pragma unroll
        for (int i = 0; i < 4; ++i) {
            int orow = orow_base + i;
            if (orow < N_NODES) {
                unsigned w[4];
                #pragma unroll
                for (int t = 0; t < 4; ++t) {
                    float v0 = acc[2 * t][i]     + bv[2 * t];
                    float v1 = acc[2 * t + 1][i] + bv[2 * t + 1];
                    w[t] = (unsigned)f2bf(v0) | ((unsigned)f2bf(v1) << 16);
                }
                uint4 pv; pv.x = w[0]; pv.y = w[1]; pv.z = w[2]; pv.w = w[3];
                *(uint4*)((unsigned short*)OutA + (size_t)orow * 128 + m * 8) = pv;
                int pk0 = __builtin_amdgcn_cvt_pk_fp8_f32(acc[8][i],  acc[9][i],  0,   false);
                pk0     = __builtin_amdgcn_cvt_pk_fp8_f32(acc[10][i], acc[11][i], pk0, true);
                int pk1 = __builtin_amdgcn_cvt_pk_fp8_f32(acc[12][i], acc[13][i], 0,   false);
                pk1     = __builtin_amdgcn_cvt_pk_fp8_f32(acc[14][i], acc[15][i], pk1, true);
                uint2 v8; v8.x = (unsigned)pk0; v8.y = (unsigned)pk1;
                *(uint2*)(OutB + (size_t)orow * 128 + m * 8) = v8;
            }
        }
    } else {  // ILV == 2
        float bv[4];
        #pragma unroll
        for (int nt = 0; nt < 4; ++nt) bv[nt] = bias[nt * 16 + m];
        #pragma unroll
        for (int i = 0; i < 4; ++i) {
            int orow = orow_base + i;
            if (orow < N_NODES) {
                float4 o;
                o.x = acc[0][i] + bv[0]; o.y = acc[1][i] + bv[1];
                o.z = acc[2][i] + bv[2]; o.w = acc[3][i] + bv[3];
                *(float4*)((float*)OutA + (size_t)orow * 64 + m * 4) = o;
                int pk = __builtin_amdgcn_cvt_pk_fp8_f32(acc[4][i], acc[5][i], 0,  false);
                pk     = __builtin_amdgcn_cvt_pk_fp8_f32(acc[6][i], acc[7][i], pk, true);
                *(unsigned*)(OutB + (size_t)orow * 64 + m * 4) = (unsigned)pk;
            }
        }
    }
}

// -------- fused: layer-1 GEMM ∪ per-bucket CSR build (independent work) ---------
// Both depend only on split_pack; merging hides the csr latency tail behind MFMA.
__global__ __launch_bounds__(256) void gemm1_csr(
        const float* __restrict__ x, const unsigned short* __restrict__ Wp1,
        const float* __restrict__ b1, unsigned short* __restrict__ xs,
        unsigned char* __restrict__ y8,
        const int* __restrict__ gcur, const int* __restrict__ bucketbuf,
        int* __restrict__ dcount, int* __restrict__ csrp)
{
    __shared__ int lcnt[128];
    const int tid = threadIdx.x;
    if (blockIdx.x < GEMM_BLOCKS) {
        gemm_body<8, 8, true, 1>(blockIdx.x, x, Wp1, b1, xs, y8, tid);
    } else {
        const int b = blockIdx.x - GEMM_BLOCKS;
        if (tid < 128) lcnt[tid] = 0;
        __syncthreads();
        int m = gcur[b]; if (m > BCAP) m = BCAP;
        const int* __restrict__ buf = bucketbuf + b * BCAP;
        for (int i = tid; i < m; i += 256) {
            int v = buf[i];
            int dloc = (v >> 17) & 127, s = v & 0x1FFFF;
            int node = (b << BSHIFT) + dloc;
            int slot = atomicAdd(&lcnt[dloc], 1);
            if (slot < MAXDEG && node < N_NODES)
                csrp[((size_t)node << 6) + slot] = s;
        }
        __syncthreads();
        if (tid < 128) {
            int node = (b << BSHIFT) + tid;
            if (node < N_NODES) {
                int c = lcnt[tid]; if (c > MAXDEG) c = MAXDEG;
                dcount[node] = c;
                int cf = (c + 15) & ~15; if (cf > MAXDEG) cf = MAXDEG;
                int* row = csrp + ((size_t)node << 6);
                for (int k = c; k < cf; ++k) row[k] = N_NODES;   // sentinel -> zero row
            }
        }
    }
}

// --------------------- layer-2 GEMM (standalone launch) -------------------------
__global__ __launch_bounds__(256) void gemm2(
        const unsigned short* __restrict__ h, const unsigned short* __restrict__ Wp2,
        const float* __restrict__ b2, float* __restrict__ tmp,
        unsigned char* __restrict__ z8)
{
    gemm_body<4, 4, false, 2>(blockIdx.x, h, Wp2, b2, tmp, z8, threadIdx.x);
}

// ---------- mean-agg + self-add: one wave per node, 4B/lane dword gathers -------
// Masked csrp read: only lanes < ceil16(dg) load their slot -> 1 cache line for
// typical deg<=16 (was 4). L1: 32 lanes/edge, fold = ONE shfl step, bf16+ReLU out.
// L2: 16 lanes/edge, fold = two steps; inputs are pi2-permuted (positional), the
// final store un-permutes: lane l writes cols {nt*16+l} -> 4 coalesced 64B runs.
template<bool L1>
__global__ __launch_bounds__(256) void agg_add(
        const unsigned char* __restrict__ feat, const int* __restrict__ csrp,
        const int* __restrict__ dcount, const void* __restrict__ self,
        void* __restrict__ out)
{
    const int LPE = L1 ? 32 : 16;      // lanes per edge (4B/lane)
    const int EPG = 64 / LPE;          // edges per load-group: 2 (L1), 4 (L2)
    const int FSH = L1 ? 7 : 6;        // log2(row bytes)
    const int NC  = L1 ? 128 : 64;     // columns

    int w = (blockIdx.x * 256 + threadIdx.x) >> 6;
    int lane = threadIdx.x & 63;
    if (w >= N_NODES) return;
    int dg = __builtin_amdgcn_readfirstlane(dcount[w]);
    int cf = (dg + 15) & ~15;          // lanes >= cf are never shfl-selected
    const int g = lane / LPE;          // edge slot within group
    const int l = lane % LPE;          // dword chunk (4 columns)
    int idxv = 0;
    if (lane < cf) idxv = csrp[((size_t)w << 6) + lane];

    floatx2 ac0 = (floatx2){0.f, 0.f};
    floatx2 ac1 = (floatx2){0.f, 0.f};
    for (int j = 0; j < dg; j += 16) {
        #pragma unroll
        for (int u = 0; u < 16 / EPG; ++u) {
            int s = __shfl(idxv, j + u * EPG + g);
            unsigned v = *(const unsigned*)(feat + ((size_t)s << FSH) + (l << 2));
            ac0 += __builtin_amdgcn_cvt_pk_f32_fp8(v, false);
            ac1 += __builtin_amdgcn_cvt_pk_f32_fp8(v, true);
        }
    }
    // fold edge-slot groups (lanes sharing l)
    #pragma unroll
    for (int delta = 32; delta >= LPE; delta >>= 1) {
        ac0.x += __shfl_down(ac0.x, delta); ac0.y += __shfl_down(ac0.y, delta);
        ac1.x += __shfl_down(ac1.x, delta); ac1.y += __shfl_down(ac1.y, delta);
    }
    if (g == 0) {                      // lanes 0..LPE-1 hold 4-col sums
        float invd = (dg > 0) ? 1.0f / (float)dg : 1.0f;
        if (L1) {                      // self bf16, out bf16 + ReLU (positional)
            uint2 sv = *(const uint2*)((const unsigned short*)self + (size_t)w * NC + l * 4);
            float h0 = bf2f(sv.x & 0xffffu)  + ac0.x * invd;
            float h1 = bf2f(sv.x >> 16)      + ac0.y * invd;
            float h2 = bf2f(sv.y & 0xffffu)  + ac1.x * invd;
            float h3 = bf2f(sv.y >> 16)      + ac1.y * invd;
            h0 = fmaxf(h0, 0.f); h1 = fmaxf(h1, 0.f);
            h2 = fmaxf(h2, 0.f); h3 = fmaxf(h3, 0.f);
            uint2 pv;
            pv.x = (unsigned)f2bf(h0) | ((unsigned)f2bf(h1) << 16);
            pv.y = (unsigned)f2bf(h2) | ((unsigned)f2bf(h3) << 16);
            *(uint2*)((unsigned short*)out + (size_t)w * NC + l * 4) = pv;
        } else {                       // self f32 (pi2), out f32 (identity)
            const float* sp = (const float*)self + (size_t)w * NC + l * 4;
            float4 s0 = *(const float4*)sp;
            float v0 = s0.x + ac0.x * invd;   // col l
            float v1 = s0.y + ac0.y * invd;   // col 16+l
            float v2 = s0.z + ac1.x * invd;   // col 32+l
            float v3 = s0.w + ac1.y * invd;   // col 48+l
            float* op = (float*)out + (size_t)w * NC;
            op[l]      = v0;
            op[16 + l] = v1;
            op[32 + l] = v2;
            op[48 + l] = v3;
        }
    }
}

extern "C" void kernel_launch(void* const* d_in, const int* in_sizes, int n_in,
                              void* d_out, int out_size, void* d_ws, size_t ws_size,
                              hipStream_t stream) {
    const float* x   = (const float*)d_in[0];
    const int*   src = (const int*)d_in[1];
    const int*   dst = (const int*)d_in[2];
    const float* Ws1 = (const float*)d_in[3];
    const float* Wn1 = (const float*)d_in[4];
    const float* b1  = (const float*)d_in[5];
    const float* Ws2 = (const float*)d_in[6];
    const float* Wn2 = (const float*)d_in[7];
    const float* b2  = (const float*)d_in[8];
    float* out = (float*)d_out;

    const size_t nd = (size_t)N_NODES * D;   // 12.8M elements
    unsigned short* h   = (unsigned short*)d_ws;          // bf16 hidden   25.6 MB
    unsigned short* xs  = h + nd;                         // bf16 self (L1) 25.6 MB
    float*          tmp = (float*)xs;                     // f32 self (L2), aliased
    unsigned char*  y8  = (unsigned char*)(xs + nd);      // fp8 y + pad   12.8 MB
    unsigned char*  z8  = y8 + (size_t)(N_NODES + 1) * D; // fp8 z + pad    6.4 MB
    int* dcount = (int*)(z8 + (size_t)(N_NODES + 1) * D_OUT);
    int* csrp   = dcount + N_NODES;                       // padded CSR    25.6 MB
    int* gcur   = csrp + (size_t)N_NODES * MAXDEG;        // (pad to 1024)
    int* bucketbuf = gcur + 1024;                         // bucket edges   9.6 MB
    unsigned short* Wp1 = (unsigned short*)(bucketbuf + (size_t)NBUCK * BCAP); // 64 KB
    unsigned short* Wp2 = Wp1 + 32768;                    // 32 KB

    hipMemsetAsync(gcur, 0, NBUCK * sizeof(int), stream);

    split_pack<<<NBLK_SPLIT + NBLK_PACK, 256, 0, stream>>>(
        src, dst, gcur, bucketbuf, Ws1, Wn1, Ws2, Wn2, Wp1, Wp2, y8, z8);

    const int agg_blocks = (N_NODES * 64 + 255) / 256;    // 25000

    // layer 1 GEMM (ILV1) fused with CSR build (independent halves)
    gemm1_csr<<<GEMM_BLOCKS + NBUCK, 256, 0, stream>>>(
        x, Wp1, b1, xs, y8, gcur, bucketbuf, dcount, csrp);
    agg_add<true ><<<agg_blocks, 256, 0, stream>>>(y8, csrp, dcount, xs, h);
    // layer 2 (ILV2; Wp2 K-rows permuted to consume interleaved h)
    gemm2<<<GEMM_BLOCKS, 256, 0, stream>>>(h, Wp2, b2, tmp, z8);
    agg_add<false><<<agg_blocks, 256, 0, stream>>>(z8, csrp, dcount, tmp, out);
}